// Round 9
// baseline (955.144 us; speedup 1.0000x reference)
//
#include <hip/hip_runtime.h>
#include <stdint.h>

typedef unsigned char u8;
typedef unsigned short u16;
typedef unsigned long long u64;
typedef __attribute__((ext_vector_type(8))) unsigned short u16x8;
typedef __attribute__((ext_vector_type(8))) __bf16 bf16x8;
typedef __attribute__((ext_vector_type(4))) float f32x4;
typedef __attribute__((ext_vector_type(2))) float f32x2;

#define NNODES 32768
#define NEDGES 131072
#define DDIM 512
#define QK4 2048   // 4*DDIM
#define MM 4096
#define UU 8

// Buffers (separate; unified row caused RMW blowup in R6):
//   Q8 [node][512]  fp8
//   KV8[node][1024] fp8, chunk c: K bytes [c*16,c*16+8), V bytes [c*16+8,c*16+16)
//   S16[node][512]  bf16
//   X  [node][512]  bf16

__device__ __forceinline__ u16 f2bf(float f) {
    unsigned u = __builtin_bit_cast(unsigned, f);
    u += 0x7FFFu + ((u >> 16) & 1u);
    return (u16)(u >> 16);
}
__device__ __forceinline__ float bf2f(u16 h) {
    return __builtin_bit_cast(float, (unsigned)h << 16);
}
__device__ __forceinline__ void enc8(const float* f, int* lo, int* hi) {
    int a = __builtin_amdgcn_cvt_pk_fp8_f32(f[0], f[1], 0, false);
    a = __builtin_amdgcn_cvt_pk_fp8_f32(f[2], f[3], a, true);
    int b = __builtin_amdgcn_cvt_pk_fp8_f32(f[4], f[5], 0, false);
    b = __builtin_amdgcn_cvt_pk_fp8_f32(f[6], f[7], b, true);
    *lo = a;
    *hi = b;
}
__device__ __forceinline__ void dec8(int lo, int hi, float* f) {
    f32x2 a = __builtin_amdgcn_cvt_pk_f32_fp8(lo, false);
    f32x2 b = __builtin_amdgcn_cvt_pk_f32_fp8(lo, true);
    f32x2 c = __builtin_amdgcn_cvt_pk_f32_fp8(hi, false);
    f32x2 d = __builtin_amdgcn_cvt_pk_f32_fp8(hi, true);
    f[0] = a[0]; f[1] = a[1]; f[2] = b[0]; f[3] = b[1];
    f[4] = c[0]; f[5] = c[1]; f[6] = d[0]; f[7] = d[1];
}

__device__ __forceinline__ void load_lds16(const void* g, void* l) {
    __builtin_amdgcn_global_load_lds((__attribute__((address_space(1))) unsigned int*)(void*)g,
                                     (__attribute__((address_space(3))) unsigned int*)l, 16, 0, 0);
}

// ---------------- fused prep: deg-zero + pooled-zero + x0 + bcat ----------------
__global__ void k_prep(const float* __restrict__ mc, const int* __restrict__ mask,
                       const float* __restrict__ sp, const float* __restrict__ cm,
                       const float* __restrict__ at, float* __restrict__ x0,
                       const float* __restrict__ bq, const float* __restrict__ bk,
                       const float* __restrict__ bv, const float* __restrict__ bs,
                       float* __restrict__ bcat,
                       int* __restrict__ deg, float* __restrict__ pooled) {
    int b = blockIdx.x;
    int t = threadIdx.x;
    if (b < 128) {  // x0 + deg zero
        int node = b * 256 + t;
        deg[node] = 0;
        int m = node >> 3, u = node & 7;
        float* o = x0 + (size_t)node * 6;
        o[0] = mc[m * 2];
        o[1] = mc[m * 2 + 1];
        o[2] = (float)mask[m];
        o[3] = sp[u];
        o[4] = cm[u * MM + m];
        o[5] = at[u * MM + m];
    } else if (b < 152) {  // bcat: 3*2048 = 6144 elems (layers 1..3)
        int i = (b - 128) * 256 + t;
        int n = i & (QK4 - 1);
        int l = i >> 11;  // 0..2
        int ty = n >> 9, nn = n & 511;
        const float* p = (ty == 0) ? bq : (ty == 1) ? bk : (ty == 2) ? bv : bs;
        bcat[(size_t)l * QK4 + n] = p[l * DDIM + nn];
    } else {  // pooled zero (2 blocks)
        pooled[(b - 152) * 256 + t] = 0.f;
    }
}

// ---------------- layer-0 attention constants: per head A[6][6], u[6], w[6], c ----------------
__global__ void k_c0(const float* __restrict__ Wq0, const float* __restrict__ bq0,
                     const float* __restrict__ Wk0, const float* __restrict__ bk0,
                     float* __restrict__ C0) {
    int i = threadIdx.x;
    if (i >= 392) return;
    int h = i / 49, r = i % 49;
    int d0 = h * 64;
    float s = 0.f;
    if (r < 36) {
        int a = r / 6, b = r % 6;
        for (int d = 0; d < 64; d++) s += Wq0[a * DDIM + d0 + d] * Wk0[b * DDIM + d0 + d];
    } else if (r < 42) {
        int a = r - 36;
        for (int d = 0; d < 64; d++) s += Wq0[a * DDIM + d0 + d] * bk0[d0 + d];
    } else if (r < 48) {
        int b = r - 42;
        for (int d = 0; d < 64; d++) s += Wk0[b * DDIM + d0 + d] * bq0[d0 + d];
    } else {
        for (int d = 0; d < 64; d++) s += bq0[d0 + d] * bk0[d0 + d];
    }
    C0[i] = s;
}

// transpose [512][512] fp32 matrices into Wt[layer][2048][512] bf16 ([n][k])
__global__ void k_wt(const float* __restrict__ Wq, const float* __restrict__ Wk,
                     const float* __restrict__ Wv, const float* __restrict__ Ws,
                     u16* __restrict__ Wt) {
    __shared__ float tile[32][33];
    int q = blockIdx.z;
    int l = q >> 2, t = q & 3;
    const float* src = ((t == 0) ? Wq : (t == 1) ? Wk : (t == 2) ? Wv : Ws) + (size_t)l * DDIM * DDIM;
    int k0 = blockIdx.x * 32, n0 = blockIdx.y * 32;
    int tx = threadIdx.x, ty = threadIdx.y;
#pragma unroll
    for (int r = 0; r < 4; r++) tile[ty + 8 * r][tx] = src[(size_t)(k0 + ty + 8 * r) * DDIM + n0 + tx];
    __syncthreads();
    u16* dst = Wt + (size_t)l * QK4 * DDIM + (size_t)t * DDIM * DDIM;
#pragma unroll
    for (int r = 0; r < 4; r++) {
        int n = n0 + ty + 8 * r;
        dst[(size_t)n * DDIM + k0 + tx] = f2bf(tile[tx][ty + 8 * r]);
    }
}

// ---------------- CSR build ----------------
__global__ void k_count(const int* __restrict__ dst, int* __restrict__ deg) {
    int e = blockIdx.x * 256 + threadIdx.x;
    if (e < NEDGES) atomicAdd(&deg[dst[e]], 1);
}

__global__ __launch_bounds__(1024) void k_scan(const int* __restrict__ deg, int* __restrict__ offs,
                                               int* __restrict__ cursor) {
    __shared__ int sums[1024];
    int t = threadIdx.x;
    int base = t * 32;
    int local[32];
    int s = 0;
#pragma unroll
    for (int i = 0; i < 32; i++) { local[i] = s; s += deg[base + i]; }
    sums[t] = s;
    __syncthreads();
    for (int d = 1; d < 1024; d <<= 1) {
        int v = (t >= d) ? sums[t - d] : 0;
        __syncthreads();
        sums[t] += v;
        __syncthreads();
    }
    int excl = (t == 0) ? 0 : sums[t - 1];
#pragma unroll
    for (int i = 0; i < 32; i++) {
        int o = excl + local[i];
        offs[base + i] = o;
        cursor[base + i] = o;
    }
    if (t == 1023) offs[NNODES] = sums[1023];
}

__global__ void k_scatter(const int* __restrict__ src, const int* __restrict__ dst,
                          int* __restrict__ cursor, int* __restrict__ ssrc) {
    int e = blockIdx.x * 256 + threadIdx.x;
    if (e < NEDGES) {
        int pos = atomicAdd(&cursor[dst[e]], 1);
        ssrc[pos] = src[e];
    }
}

// ---------------- fused layer-0 conv: 6-dim attention + projection -> X bf16 ----------------
__global__ __launch_bounds__(256) void k_attn0(const float* __restrict__ x0, const float* __restrict__ C0,
                                               const float* __restrict__ Wv0, const float* __restrict__ bv0,
                                               const float* __restrict__ Ws0, const float* __restrict__ bs0,
                                               const int* __restrict__ offs, const int* __restrict__ ssrc,
                                               u16* __restrict__ Xout) {
    const int lane = threadIdx.x & 63;
    const int wv = threadIdx.x >> 6;
    const int h = lane & 7;
    float wV[8][6], wS[8][6], bV[8], bS[8];
#pragma unroll
    for (int j = 0; j < 8; ++j) {
        int c = lane + 64 * j;
        bV[j] = bv0[c];
        bS[j] = bs0[c];
#pragma unroll
        for (int a = 0; a < 6; ++a) {
            wV[j][a] = Wv0[a * DDIM + c];
            wS[j][a] = Ws0[a * DDIM + c];
        }
    }
    float Ah[36], uh[6], wh[6], ch;
#pragma unroll
    for (int r = 0; r < 36; ++r) Ah[r] = C0[h * 49 + r];
#pragma unroll
    for (int a = 0; a < 6; ++a) uh[a] = C0[h * 49 + 36 + a];
#pragma unroll
    for (int a = 0; a < 6; ++a) wh[a] = C0[h * 49 + 42 + a];
    ch = C0[h * 49 + 48];

    int node0 = (blockIdx.x * 4 + wv) * 8;
    for (int nn = 0; nn < 8; ++nn) {
        int node = node0 + nn;
        float xi[6];
#pragma unroll
        for (int a = 0; a < 6; ++a) xi[a] = x0[(size_t)node * 6 + a];
        float m = -INFINITY, l = 0.f;
        float xh[6];
#pragma unroll
        for (int a = 0; a < 6; ++a) xh[a] = 0.f;
        const int e0 = offs[node], e1 = offs[node + 1];
        for (int e = e0; e < e1; ++e) {
            int s = ssrc[e];
            float xj[6];
#pragma unroll
            for (int a = 0; a < 6; ++a) xj[a] = x0[(size_t)s * 6 + a];
            float alpha = ch;
#pragma unroll
            for (int a = 0; a < 6; ++a) {
                float t = uh[a];
#pragma unroll
                for (int b = 0; b < 6; ++b) t += Ah[a * 6 + b] * xj[b];
                alpha += xi[a] * t;
            }
#pragma unroll
            for (int b = 0; b < 6; ++b) alpha += wh[b] * xj[b];
            alpha *= 0.125f;
            float nm = fmaxf(m, alpha);
            float corr = __expf(m - nm);
            float p = __expf(alpha - nm);
            l = l * corr + p;
#pragma unroll
            for (int a = 0; a < 6; ++a) xh[a] = xh[a] * corr + p * xj[a];
            m = nm;
        }
#pragma unroll
        for (int j = 0; j < 8; ++j) {
            float lb = __shfl(l, j, 64);
            float num = lb * bV[j];
#pragma unroll
            for (int a = 0; a < 6; ++a) num += __shfl(xh[a], j, 64) * wV[j][a];
            float skip = bS[j];
#pragma unroll
            for (int a = 0; a < 6; ++a) skip += xi[a] * wS[j][a];
            float r = num / (lb + 1e-16f) + skip;
            Xout[(size_t)node * DDIM + lane + 64 * j] = f2bf(fmaxf(r, 0.f));
        }
    }
}

// ---------------- main MFMA GEMM (bf16): X[32768,512] @ Wt[2048,512]^T -> Q8/KV8/S16 ----------------
__global__ __launch_bounds__(256, 5) void k_gemm(const u16* __restrict__ X, const u16* __restrict__ Wt,
                                                 const float* __restrict__ bcat, u8* __restrict__ Q8,
                                                 u8* __restrict__ KV8, u16* __restrict__ S16) {
    __shared__ __align__(16) u16 smem[2 * 128 * 64];  // 32 KB
    u16* As = smem;
    u16* Bs = smem + 128 * 64;
    const int tid = threadIdx.x;
    const int lane = tid & 63;
    const int w = tid >> 6;
    const int wm = w & 1, wn = w >> 1;
    const int bid = blockIdx.x;
    const int xcd = bid & 7;
    const int s = bid >> 3;
    const size_t arow0 = (size_t)(xcd * 32 + (s >> 4)) * 128;
    const size_t brow0 = (size_t)(s & 15) * 128;
    const int bt = (int)(brow0 >> 7);

    f32x4 acc[4][4];
#pragma unroll
    for (int i = 0; i < 4; i++)
#pragma unroll
        for (int j = 0; j < 4; j++) acc[i][j] = (f32x4){0.f, 0.f, 0.f, 0.f};

    const int la = lane & 7;
    const int quad = lane >> 4;
    const int lm = lane & 15;

    for (int kt = 0; kt < 8; ++kt) {
        const int k0 = kt * 64;
#pragma unroll
        for (int t = 0; t < 4; ++t) {
            int idx = (w * 4 + t) * 64 + lane;
            int m = idx >> 3;
            int c = la ^ (m & 7);
            const u16* ga = X + (arow0 + m) * DDIM + (k0 + c * 8);
            const u16* gb = Wt + (brow0 + m) * DDIM + (k0 + c * 8);
            load_lds16(ga, &As[(size_t)((w * 4 + t) * 64) * 8]);
            load_lds16(gb, &Bs[(size_t)((w * 4 + t) * 64) * 8]);
        }
        __syncthreads();
#pragma unroll
        for (int kk = 0; kk < 2; ++kk) {
            bf16x8 af[4], bfg[4];
            int c = kk * 4 + quad;
#pragma unroll
            for (int i = 0; i < 4; ++i) {
                int m = wm * 64 + i * 16 + lm;
                int slot = m * 8 + (c ^ (m & 7));
                af[i] = *(const bf16x8*)&As[(size_t)slot * 8];
            }
#pragma unroll
            for (int j = 0; j < 4; ++j) {
                int n = wn * 64 + j * 16 + lm;
                int slot = n * 8 + (c ^ (n & 7));
                bfg[j] = *(const bf16x8*)&Bs[(size_t)slot * 8];
            }
#pragma unroll
            for (int i = 0; i < 4; ++i)
#pragma unroll
                for (int j = 0; j < 4; ++j)
                    acc[i][j] = __builtin_amdgcn_mfma_f32_16x16x32_bf16(af[i], bfg[j], acc[i][j], 0, 0, 0);
        }
        __syncthreads();
    }

    float biasv[4];
#pragma unroll
    for (int j = 0; j < 4; ++j) biasv[j] = bcat[brow0 + wn * 64 + j * 16 + lm];

    u16* stg = smem;  // [4 waves][32 rows][72 u16]
    const int chunk = lane & 7;
    const int rrow = lane >> 3;
    const int colbase = (int)brow0 + wn * 64 + chunk * 8;
#pragma unroll
    for (int p = 0; p < 2; ++p) {
        __syncthreads();
#pragma unroll
        for (int ii = 0; ii < 2; ++ii) {
            int i = p * 2 + ii;
#pragma unroll
            for (int j = 0; j < 4; ++j) {
#pragma unroll
                for (int r = 0; r < 4; ++r) {
                    int lr = ii * 16 + quad * 4 + r;
                    int lc = j * 16 + lm;
                    stg[(size_t)(w * 32 + lr) * 72 + lc] = f2bf(acc[i][j][r] + biasv[j]);
                }
            }
        }
        __syncthreads();
#pragma unroll
        for (int it = 0; it < 4; ++it) {
            int row = it * 8 + rrow;
            u16x8 v = *(const u16x8*)&stg[(size_t)(w * 32 + row) * 72 + chunk * 8];
            size_t grow = arow0 + wm * 64 + p * 32 + row;
            if (bt < 4) {
                float f[8];
#pragma unroll
                for (int j = 0; j < 8; j++) f[j] = bf2f(v[j]);
                int lo, hi;
                enc8(f, &lo, &hi);
                *(int2*)(Q8 + grow * 512 + colbase) = make_int2(lo, hi);
            } else if (bt < 12) {
                float f[8];
#pragma unroll
                for (int j = 0; j < 8; j++) f[j] = bf2f(v[j]);
                int lo, hi;
                enc8(f, &lo, &hi);
                int kvcol = (bt < 8) ? (colbase - 512) : (colbase - 1024);
                int ofs = (bt < 8) ? 0 : 8;
                *(int2*)(KV8 + grow * 1024 + (size_t)(kvcol >> 3) * 16 + ofs) = make_int2(lo, hi);
            } else {
                *(u16x8*)(S16 + grow * 512 + (colbase - 1536)) = v;
            }
        }
    }
}

// ---------------- attention (layers 1-3): one wave per TWO dst nodes, interleaved streams ----------------
__global__ __launch_bounds__(256) void k_attn(const u8* __restrict__ Q8, const u8* __restrict__ KV8,
                                              const u16* __restrict__ S16, const int* __restrict__ offs,
                                              const int* __restrict__ ssrc, u16* __restrict__ Xout) {
    const int lane = threadIdx.x & 63;
    const int w = threadIdx.x >> 6;
    const int nodeA = (blockIdx.x * 4 + w) * 2;
    const int nodeB = nodeA + 1;
    const u64 q8a = *(const u64*)(Q8 + (size_t)nodeA * 512 + (size_t)lane * 8);
    const u64 q8b = *(const u64*)(Q8 + (size_t)nodeB * 512 + (size_t)lane * 8);
    float qA[8], qB[8];
    dec8((int)(q8a & 0xFFFFFFFFull), (int)(q8a >> 32), qA);
    dec8((int)(q8b & 0xFFFFFFFFull), (int)(q8b >> 32), qB);
    float mA = -INFINITY, lA = 0.f, mB = -INFINITY, lB = 0.f;
    float accA[8], accB[8];
#pragma unroll
    for (int j = 0; j < 8; j++) { accA[j] = 0.f; accB[j] = 0.f; }
    int eA = offs[nodeA];
    const int e1A = offs[nodeA + 1];
    int eB = e1A;  // offs[nodeB] == offs[nodeA+1]
    const int e1B = offs[nodeB + 1];
    while (eA < e1A || eB < e1B) {
        int nbA = e1A - eA; if (nbA > 4) nbA = 4; if (nbA < 0) nbA = 0;
        int nbB = e1B - eB; if (nbB > 4) nbB = 4; if (nbB < 0) nbB = 0;
        int4 ka[4], kb[4];
#pragma unroll
        for (int i = 0; i < 4; ++i)
            if (i < nbA) ka[i] = *(const int4*)(KV8 + (size_t)ssrc[eA + i] * 1024 + (size_t)lane * 16);
#pragma unroll
        for (int i = 0; i < 4; ++i)
            if (i < nbB) kb[i] = *(const int4*)(KV8 + (size_t)ssrc[eB + i] * 1024 + (size_t)lane * 16);
#pragma unroll
        for (int i = 0; i < 4; ++i) {
            if (i >= nbA) break;
            int4 kv = ka[i];
            f32x2 k01 = __builtin_amdgcn_cvt_pk_f32_fp8(kv.x, false);
            f32x2 k23 = __builtin_amdgcn_cvt_pk_f32_fp8(kv.x, true);
            f32x2 k45 = __builtin_amdgcn_cvt_pk_f32_fp8(kv.y, false);
            f32x2 k67 = __builtin_amdgcn_cvt_pk_f32_fp8(kv.y, true);
            float d = qA[0] * k01[0] + qA[1] * k01[1] + qA[2] * k23[0] + qA[3] * k23[1] +
                      qA[4] * k45[0] + qA[5] * k45[1] + qA[6] * k67[0] + qA[7] * k67[1];
            d += __shfl_xor(d, 1, 64);
            d += __shfl_xor(d, 2, 64);
            d += __shfl_xor(d, 4, 64);
            float a = d * 0.125f;
            float nm = fmaxf(mA, a);
            float corr = __expf(mA - nm);
            float p = __expf(a - nm);
            lA = lA * corr + p;
            f32x2 v01 = __builtin_amdgcn_cvt_pk_f32_fp8(kv.z, false);
            f32x2 v23 = __builtin_amdgcn_cvt_pk_f32_fp8(kv.z, true);
            f32x2 v45 = __builtin_amdgcn_cvt_pk_f32_fp8(kv.w, false);
            f32x2 v67 = __builtin_amdgcn_cvt_pk_f32_fp8(kv.w, true);
            accA[0] = accA[0] * corr + p * v01[0];
            accA[1] = accA[1] * corr + p * v01[1];
            accA[2] = accA[2] * corr + p * v23[0];
            accA[3] = accA[3] * corr + p * v23[1];
            accA[4] = accA[4] * corr + p * v45[0];
            accA[5] = accA[5] * corr + p * v45[1];
            accA[6] = accA[6] * corr + p * v67[0];
            accA[7] = accA[7] * corr + p * v67[1];
            mA = nm;
        }
#pragma unroll
        for (int i = 0; i < 4; ++i) {
            if (i >= nbB) break;
            int4 kv = kb[i];
            f32x2 k01 = __builtin_amdgcn_cvt_pk_f32_fp8(kv.x, false);
            f32x2 k23 = __builtin_amdgcn_cvt_pk_f32_fp8(kv.x, true);
            f32x2 k45 = __builtin_amdgcn_cvt_pk_f32_fp8(kv.y, false);
            f32x2 k67 = __builtin_amdgcn_cvt_pk_f32_fp8(kv.y, true);
            float d = qB[0] * k01[0] + qB[1] * k01[1] + qB[2] * k23[0] + qB[3] * k23[1] +
                      qB[4] * k45[0] + qB[5] * k45[1] + qB[6] * k67[0] + qB[7] * k67[1];
            d += __shfl_xor(d, 1, 64);
            d += __shfl_xor(d, 2, 64);
            d += __shfl_xor(d, 4, 64);
            float a = d * 0.125f;
            float nm = fmaxf(mB, a);
            float corr = __expf(mB - nm);
            float p = __expf(a - nm);
            lB = lB * corr + p;
            f32x2 v01 = __builtin_amdgcn_cvt_pk_f32_fp8(kv.z, false);
            f32x2 v23 = __builtin_amdgcn_cvt_pk_f32_fp8(kv.z, true);
            f32x2 v45 = __builtin_amdgcn_cvt_pk_f32_fp8(kv.w, false);
            f32x2 v67 = __builtin_amdgcn_cvt_pk_f32_fp8(kv.w, true);
            accB[0] = accB[0] * corr + p * v01[0];
            accB[1] = accB[1] * corr + p * v01[1];
            accB[2] = accB[2] * corr + p * v23[0];
            accB[3] = accB[3] * corr + p * v23[1];
            accB[4] = accB[4] * corr + p * v45[0];
            accB[5] = accB[5] * corr + p * v45[1];
            accB[6] = accB[6] * corr + p * v67[0];
            accB[7] = accB[7] * corr + p * v67[1];
            mB = nm;
        }
        eA += nbA;
        eB += nbB;
    }
    const u16x8 svA = *(const u16x8*)(S16 + (size_t)nodeA * 512 + (size_t)lane * 8);
    const u16x8 svB = *(const u16x8*)(S16 + (size_t)nodeB * 512 + (size_t)lane * 8);
    float invA = 1.0f / (lA + 1e-16f);
    float invB = 1.0f / (lB + 1e-16f);
    u16x8 oA, oB;
#pragma unroll
    for (int j = 0; j < 8; j++) {
        oA[j] = f2bf(fmaxf(accA[j] * invA + bf2f(svA[j]), 0.f));
        oB[j] = f2bf(fmaxf(accB[j] * invB + bf2f(svB[j]), 0.f));
    }
    *(u16x8*)(Xout + (size_t)nodeA * DDIM + (size_t)lane * 8) = oA;
    *(u16x8*)(Xout + (size_t)nodeB * DDIM + (size_t)lane * 8) = oB;
}

// ---------------- pooling (bf16 input, vectorized) ----------------
__global__ __launch_bounds__(256) void k_pool(const u16* __restrict__ X, float* __restrict__ pooled) {
    __shared__ float red[4][64][8];
    int t = threadIdx.x;
    int chunk = t & 63;
    int rofs = t >> 6;
    float s[8];
#pragma unroll
    for (int j = 0; j < 8; j++) s[j] = 0.f;
    int nd0 = blockIdx.x * 256;
    for (int nd = nd0 + rofs; nd < nd0 + 256; nd += 4) {
        u16x8 v = *(const u16x8*)&X[(size_t)nd * DDIM + chunk * 8];
#pragma unroll
        for (int j = 0; j < 8; j++) s[j] += bf2f(v[j]);
    }
#pragma unroll
    for (int j = 0; j < 8; j++) red[rofs][chunk][j] = s[j];
    __syncthreads();
    if (t < 64) {
#pragma unroll
        for (int j = 0; j < 8; j++) {
            float o = red[0][t][j] + red[1][t][j] + red[2][t][j] + red[3][t][j];
            atomicAdd(&pooled[t * 8 + j], o);
        }
    }
}

// ---------------- heads: emb + hidden layers + critic ----------------
__global__ __launch_bounds__(1024) void k_heads(const float* __restrict__ pooled, const float* __restrict__ fcW,
                                                const float* __restrict__ fcb, const float* __restrict__ ui,
                                                const float* __restrict__ sp, const float* __restrict__ aW1,
                                                const float* __restrict__ ab1, const float* __restrict__ cW1,
                                                const float* __restrict__ cb1, const float* __restrict__ cW2,
                                                const float* __restrict__ cb2, float* __restrict__ hidden_a,
                                                float* __restrict__ out) {
    __shared__ float spool[512];
    __shared__ float semb[64];
    __shared__ float shc[8][128];
    int t = threadIdx.x;
    if (t < 512) spool[t] = pooled[t] * (1.0f / 32768.0f);
    __syncthreads();
    if (t < 64) {
        float s = fcb[t];
        for (int k = 0; k < 512; k++) s += spool[k] * fcW[k * 64 + t];
        semb[t] = s;
    }
    __syncthreads();
    int u = t >> 7, j = t & 127;
    float u0 = ui[u * 2], u1 = ui[u * 2 + 1], uspd = sp[u];
    float ha = ab1[j] + u0 * aW1[j] + u1 * aW1[128 + j] + uspd * aW1[66 * 128 + j];
    float hc = cb1[j] + u0 * cW1[j] + u1 * cW1[128 + j] + uspd * cW1[66 * 128 + j];
    for (int k = 0; k < 64; k++) {
        float e = semb[k];
        ha += e * aW1[(2 + k) * 128 + j];
        hc += e * cW1[(2 + k) * 128 + j];
    }
    ha = fmaxf(ha, 0.f);
    hc = fmaxf(hc, 0.f);
    hidden_a[u * 128 + j] = ha;
    shc[u][j] = hc;
    __syncthreads();
    if (t < 8) {
        float s = cb2[0];
        for (int k = 0; k < 128; k++) s += shc[t][k] * cW2[k];
        out[NNODES + t] = s;
    }
}

// ---------------- actor logits + softmax ----------------
__global__ __launch_bounds__(1024) void k_actor(const float* __restrict__ hidden_a, const float* __restrict__ aW2,
                                                const float* __restrict__ ab2, float* __restrict__ out) {
    __shared__ float h[128];
    __shared__ float red[1024];
    int u = blockIdx.x, t = threadIdx.x;
    if (t < 128) h[t] = hidden_a[u * 128 + t];
    __syncthreads();
    float lg[4];
#pragma unroll
    for (int p = 0; p < 4; p++) {
        int mcol = t + p * 1024;
        float s = ab2[mcol];
        for (int k = 0; k < 128; k++) s += h[k] * aW2[(size_t)k * MM + mcol];
        lg[p] = s;
    }
    float mx = fmaxf(fmaxf(lg[0], lg[1]), fmaxf(lg[2], lg[3]));
    red[t] = mx;
    __syncthreads();
    for (int s2 = 512; s2 > 0; s2 >>= 1) {
        if (t < s2) red[t] = fmaxf(red[t], red[t + s2]);
        __syncthreads();
    }
    mx = red[0];
    __syncthreads();
    float e[4], sum = 0.f;
#pragma unroll
    for (int p = 0; p < 4; p++) {
        e[p] = __expf(lg[p] - mx);
        sum += e[p];
    }
    red[t] = sum;
    __syncthreads();
    for (int s2 = 512; s2 > 0; s2 >>= 1) {
        if (t < s2) red[t] += red[t + s2];
        __syncthreads();
    }
    float inv = 1.0f / red[0];
#pragma unroll
    for (int p = 0; p < 4; p++) out[(size_t)u * MM + t + p * 1024] = e[p] * inv;
}

extern "C" void kernel_launch(void* const* d_in, const int* in_sizes, int n_in,
                              void* d_out, int out_size, void* d_ws, size_t ws_size,
                              hipStream_t stream) {
    const float* mc   = (const float*)d_in[0];
    const float* ui   = (const float*)d_in[1];
    const float* sp   = (const float*)d_in[2];
    const float* cm   = (const float*)d_in[3];
    const float* at   = (const float*)d_in[4];
    const int*   eidx = (const int*)d_in[5];
    const int*   mask = (const int*)d_in[7];
    const float* Wq0 = (const float*)d_in[8];
    const float* bq0 = (const float*)d_in[9];
    const float* Wk0 = (const float*)d_in[10];
    const float* bk0 = (const float*)d_in[11];
    const float* Wv0 = (const float*)d_in[12];
    const float* bv0 = (const float*)d_in[13];
    const float* Ws0 = (const float*)d_in[14];
    const float* bs0 = (const float*)d_in[15];
    const float* Wq = (const float*)d_in[16];
    const float* bq = (const float*)d_in[17];
    const float* Wk = (const float*)d_in[18];
    const float* bk = (const float*)d_in[19];
    const float* Wv = (const float*)d_in[20];
    const float* bv = (const float*)d_in[21];
    const float* Ws = (const float*)d_in[22];
    const float* bs = (const float*)d_in[23];
    const float* fcW = (const float*)d_in[24];
    const float* fcb = (const float*)d_in[25];
    const float* aW1 = (const float*)d_in[26];
    const float* ab1 = (const float*)d_in[27];
    const float* aW2 = (const float*)d_in[28];
    const float* ab2 = (const float*)d_in[29];
    const float* cW1 = (const float*)d_in[30];
    const float* cb1 = (const float*)d_in[31];
    const float* cW2 = (const float*)d_in[32];
    const float* cb2 = (const float*)d_in[33];
    float* out = (float*)d_out;

    const int* esrc = eidx;
    const int* edst = eidx + NEDGES;

    char* ws = (char*)d_ws;
    size_t off = 0;
    auto alloc = [&](size_t bytes) -> void* {
        void* p = ws + off;
        off += (bytes + 255) & ~(size_t)255;
        return p;
    };
    u8*    Q8    = (u8*)alloc((size_t)NNODES * 512);         // 16 MB fp8
    u8*    KV8   = (u8*)alloc((size_t)NNODES * 1024);        // 32 MB fp8 interleaved
    u16*   S16   = (u16*)alloc((size_t)NNODES * 512 * 2);    // 32 MB bf16
    u16*   X     = (u16*)alloc((size_t)NNODES * DDIM * 2);   // 32 MB bf16
    u16*   Wt    = (u16*)alloc((size_t)3 * QK4 * DDIM * 2);  // 6 MB
    float* bcat  = (float*)alloc((size_t)3 * QK4 * 4);
    float* C0    = (float*)alloc((size_t)392 * 4);
    float* x0    = (float*)alloc((size_t)NNODES * 6 * 4);
    int*   deg   = (int*)alloc((size_t)NNODES * 4);
    int*   offs  = (int*)alloc((size_t)(NNODES + 1) * 4);
    int*   cursor= (int*)alloc((size_t)NNODES * 4);
    int*   ssrc  = (int*)alloc((size_t)NEDGES * 4);
    float* pooled= (float*)alloc((size_t)512 * 4);
    float* hidden_a = (float*)alloc((size_t)UU * 128 * 4);
    (void)ws_size; (void)in_sizes; (void)n_in; (void)out_size;

    // prep
    k_prep<<<154, 256, 0, stream>>>(mc, mask, sp, cm, at, x0, bq, bk, bv, bs, bcat, deg, pooled);
    k_c0<<<1, 512, 0, stream>>>(Wq0, bq0, Wk0, bk0, C0);
    {
        dim3 g(16, 16, 12), b(32, 8);
        k_wt<<<g, b, 0, stream>>>(Wq, Wk, Wv, Ws, Wt);
    }
    // CSR
    k_count<<<NEDGES / 256, 256, 0, stream>>>(edst, deg);
    k_scan<<<1, 1024, 0, stream>>>(deg, offs, cursor);
    k_scatter<<<NEDGES / 256, 256, 0, stream>>>(esrc, edst, cursor, ssrc);

    // layer 0: fused 6-dim attention + projection
    k_attn0<<<1024, 256, 0, stream>>>(x0, C0, Wv0, bv0, Ws0, bs0, offs, ssrc, X);

    // layers 1..3
    for (int l = 0; l < 3; ++l) {
        k_gemm<<<4096, 256, 0, stream>>>(X, Wt + (size_t)l * QK4 * DDIM, bcat + (size_t)l * QK4, Q8, KV8, S16);
        k_attn<<<4096, 256, 0, stream>>>(Q8, KV8, S16, offs, ssrc, X);
    }

    // pool + heads
    k_pool<<<128, 256, 0, stream>>>(X, pooled);
    k_heads<<<1, 1024, 0, stream>>>(pooled, fcW, fcb, ui, sp, aW1, ab1, cW1, cb1, cW2, cb2, hidden_a, out);
    k_actor<<<UU, 1024, 0, stream>>>(hidden_a, aW2, ab2, out);
}

// Round 10
// 639.170 us; speedup vs baseline: 1.4944x; 1.4944x over previous
//
#include <hip/hip_runtime.h>
#include <stdint.h>

typedef unsigned char u8;
typedef unsigned short u16;
typedef unsigned long long u64;
typedef __attribute__((ext_vector_type(8))) unsigned short u16x8;
typedef __attribute__((ext_vector_type(8))) __bf16 bf16x8;
typedef __attribute__((ext_vector_type(4))) float f32x4;
typedef __attribute__((ext_vector_type(2))) float f32x2;

#define NNODES 32768
#define NEDGES 131072
#define DDIM 512
#define QK4 2048   // 4*DDIM
#define MM 4096
#define UU 8

// Buffers:
//   Q8 [node][512]  fp8
//   KV8[node][1024] fp8, chunk c: K cols c*8..c*8+7 at bytes [c*16,c*16+8), V same cols at [c*16+8,c*16+16)
//   S16[node][512]  bf16
//   X  [node][512]  bf16
// Wt N-order is PERMUTED in the KV region so gemm's KV8 stores are linear (full-line, no RMW):
//   Wt row n: n<512 -> Q col n; 512<=n<1536: g=n-512,c=g>>4,r=g&15, r<8 -> K col c*8+r else V col c*8+r-8;
//   n>=1536 -> S col n-1536.  bcat permuted identically.

__device__ __forceinline__ u16 f2bf(float f) {
    unsigned u = __builtin_bit_cast(unsigned, f);
    u += 0x7FFFu + ((u >> 16) & 1u);
    return (u16)(u >> 16);
}
__device__ __forceinline__ float bf2f(u16 h) {
    return __builtin_bit_cast(float, (unsigned)h << 16);
}
__device__ __forceinline__ void enc8(const float* f, int* lo, int* hi) {
    int a = __builtin_amdgcn_cvt_pk_fp8_f32(f[0], f[1], 0, false);
    a = __builtin_amdgcn_cvt_pk_fp8_f32(f[2], f[3], a, true);
    int b = __builtin_amdgcn_cvt_pk_fp8_f32(f[4], f[5], 0, false);
    b = __builtin_amdgcn_cvt_pk_fp8_f32(f[6], f[7], b, true);
    *lo = a;
    *hi = b;
}
__device__ __forceinline__ void dec8(int lo, int hi, float* f) {
    f32x2 a = __builtin_amdgcn_cvt_pk_f32_fp8(lo, false);
    f32x2 b = __builtin_amdgcn_cvt_pk_f32_fp8(lo, true);
    f32x2 c = __builtin_amdgcn_cvt_pk_f32_fp8(hi, false);
    f32x2 d = __builtin_amdgcn_cvt_pk_f32_fp8(hi, true);
    f[0] = a[0]; f[1] = a[1]; f[2] = b[0]; f[3] = b[1];
    f[4] = c[0]; f[5] = c[1]; f[6] = d[0]; f[7] = d[1];
}

__device__ __forceinline__ void load_lds16(const void* g, void* l) {
    __builtin_amdgcn_global_load_lds((__attribute__((address_space(1))) unsigned int*)(void*)g,
                                     (__attribute__((address_space(3))) unsigned int*)l, 16, 0, 0);
}

// ---------------- fused prep: deg-zero + pooled-zero + x0 + bcat (KV-permuted) ----------------
__global__ void k_prep(const float* __restrict__ mc, const int* __restrict__ mask,
                       const float* __restrict__ sp, const float* __restrict__ cm,
                       const float* __restrict__ at, float* __restrict__ x0,
                       const float* __restrict__ bq, const float* __restrict__ bk,
                       const float* __restrict__ bv, const float* __restrict__ bs,
                       float* __restrict__ bcat,
                       int* __restrict__ deg, float* __restrict__ pooled) {
    int b = blockIdx.x;
    int t = threadIdx.x;
    if (b < 128) {  // x0 + deg zero
        int node = b * 256 + t;
        deg[node] = 0;
        int m = node >> 3, u = node & 7;
        float* o = x0 + (size_t)node * 6;
        o[0] = mc[m * 2];
        o[1] = mc[m * 2 + 1];
        o[2] = (float)mask[m];
        o[3] = sp[u];
        o[4] = cm[u * MM + m];
        o[5] = at[u * MM + m];
    } else if (b < 152) {  // bcat: 3*2048 elems, KV-permuted
        int i = (b - 128) * 256 + t;
        int n = i & (QK4 - 1);
        int l = i >> 11;  // 0..2
        const float* p;
        int col;
        if (n < 512) { p = bq; col = n; }
        else if (n < 1536) {
            int g = n - 512, c = g >> 4, r = g & 15;
            if (r < 8) { p = bk; col = c * 8 + r; }
            else { p = bv; col = c * 8 + r - 8; }
        } else { p = bs; col = n - 1536; }
        bcat[(size_t)l * QK4 + n] = p[l * DDIM + col];
    } else {  // pooled zero (2 blocks)
        pooled[(b - 152) * 256 + t] = 0.f;
    }
}

// ---------------- layer-0 attention constants: per head A[6][6], u[6], w[6], c ----------------
__global__ void k_c0(const float* __restrict__ Wq0, const float* __restrict__ bq0,
                     const float* __restrict__ Wk0, const float* __restrict__ bk0,
                     float* __restrict__ C0) {
    int i = threadIdx.x;
    if (i >= 392) return;
    int h = i / 49, r = i % 49;
    int d0 = h * 64;
    float s = 0.f;
    if (r < 36) {
        int a = r / 6, b = r % 6;
        for (int d = 0; d < 64; d++) s += Wq0[a * DDIM + d0 + d] * Wk0[b * DDIM + d0 + d];
    } else if (r < 42) {
        int a = r - 36;
        for (int d = 0; d < 64; d++) s += Wq0[a * DDIM + d0 + d] * bk0[d0 + d];
    } else if (r < 48) {
        int b = r - 42;
        for (int d = 0; d < 64; d++) s += Wk0[b * DDIM + d0 + d] * bq0[d0 + d];
    } else {
        for (int d = 0; d < 64; d++) s += bq0[d0 + d] * bk0[d0 + d];
    }
    C0[i] = s;
}

// transpose [512][512] fp32 into Wt[layer][2048][512] bf16, KV rows interleaved (see header comment)
__global__ void k_wt(const float* __restrict__ Wq, const float* __restrict__ Wk,
                     const float* __restrict__ Wv, const float* __restrict__ Ws,
                     u16* __restrict__ Wt) {
    __shared__ float tile[32][33];
    int q = blockIdx.z;
    int l = q >> 2, t = q & 3;
    const float* src = ((t == 0) ? Wq : (t == 1) ? Wk : (t == 2) ? Wv : Ws) + (size_t)l * DDIM * DDIM;
    int k0 = blockIdx.x * 32, n0 = blockIdx.y * 32;
    int tx = threadIdx.x, ty = threadIdx.y;
#pragma unroll
    for (int r = 0; r < 4; r++) tile[ty + 8 * r][tx] = src[(size_t)(k0 + ty + 8 * r) * DDIM + n0 + tx];
    __syncthreads();
    u16* dst = Wt + (size_t)l * QK4 * DDIM;
#pragma unroll
    for (int r = 0; r < 4; r++) {
        int nn = n0 + ty + 8 * r;  // source col in W_t
        int n;                     // permuted dst row
        if (t == 0) n = nn;
        else if (t == 1) n = 512 + ((nn >> 3) << 4) + (nn & 7);
        else if (t == 2) n = 512 + ((nn >> 3) << 4) + 8 + (nn & 7);
        else n = 1536 + nn;
        dst[(size_t)n * DDIM + k0 + tx] = f2bf(tile[tx][ty + 8 * r]);
    }
}

// ---------------- CSR build ----------------
__global__ void k_count(const int* __restrict__ dst, int* __restrict__ deg) {
    int e = blockIdx.x * 256 + threadIdx.x;
    if (e < NEDGES) atomicAdd(&deg[dst[e]], 1);
}

__global__ __launch_bounds__(1024) void k_scan(const int* __restrict__ deg, int* __restrict__ offs,
                                               int* __restrict__ cursor) {
    __shared__ int sums[1024];
    int t = threadIdx.x;
    int base = t * 32;
    int local[32];
    int s = 0;
#pragma unroll
    for (int i = 0; i < 32; i++) { local[i] = s; s += deg[base + i]; }
    sums[t] = s;
    __syncthreads();
    for (int d = 1; d < 1024; d <<= 1) {
        int v = (t >= d) ? sums[t - d] : 0;
        __syncthreads();
        sums[t] += v;
        __syncthreads();
    }
    int excl = (t == 0) ? 0 : sums[t - 1];
#pragma unroll
    for (int i = 0; i < 32; i++) {
        int o = excl + local[i];
        offs[base + i] = o;
        cursor[base + i] = o;
    }
    if (t == 1023) offs[NNODES] = sums[1023];
}

__global__ void k_scatter(const int* __restrict__ src, const int* __restrict__ dst,
                          int* __restrict__ cursor, int* __restrict__ ssrc) {
    int e = blockIdx.x * 256 + threadIdx.x;
    if (e < NEDGES) {
        int pos = atomicAdd(&cursor[dst[e]], 1);
        ssrc[pos] = src[e];
    }
}

// ---------------- fused layer-0 conv: 6-dim attention + projection -> X bf16 ----------------
__global__ __launch_bounds__(256) void k_attn0(const float* __restrict__ x0, const float* __restrict__ C0,
                                               const float* __restrict__ Wv0, const float* __restrict__ bv0,
                                               const float* __restrict__ Ws0, const float* __restrict__ bs0,
                                               const int* __restrict__ offs, const int* __restrict__ ssrc,
                                               u16* __restrict__ Xout) {
    const int lane = threadIdx.x & 63;
    const int wv = threadIdx.x >> 6;
    const int h = lane & 7;
    float wV[8][6], wS[8][6], bV[8], bS[8];
#pragma unroll
    for (int j = 0; j < 8; ++j) {
        int c = lane + 64 * j;
        bV[j] = bv0[c];
        bS[j] = bs0[c];
#pragma unroll
        for (int a = 0; a < 6; ++a) {
            wV[j][a] = Wv0[a * DDIM + c];
            wS[j][a] = Ws0[a * DDIM + c];
        }
    }
    float Ah[36], uh[6], wh[6], ch;
#pragma unroll
    for (int r = 0; r < 36; ++r) Ah[r] = C0[h * 49 + r];
#pragma unroll
    for (int a = 0; a < 6; ++a) uh[a] = C0[h * 49 + 36 + a];
#pragma unroll
    for (int a = 0; a < 6; ++a) wh[a] = C0[h * 49 + 42 + a];
    ch = C0[h * 49 + 48];

    int node0 = (blockIdx.x * 4 + wv) * 8;
    for (int nn = 0; nn < 8; ++nn) {
        int node = node0 + nn;
        float xi[6];
#pragma unroll
        for (int a = 0; a < 6; ++a) xi[a] = x0[(size_t)node * 6 + a];
        float m = -INFINITY, l = 0.f;
        float xh[6];
#pragma unroll
        for (int a = 0; a < 6; ++a) xh[a] = 0.f;
        const int e0 = offs[node], e1 = offs[node + 1];
        for (int e = e0; e < e1; ++e) {
            int s = ssrc[e];
            float xj[6];
#pragma unroll
            for (int a = 0; a < 6; ++a) xj[a] = x0[(size_t)s * 6 + a];
            float alpha = ch;
#pragma unroll
            for (int a = 0; a < 6; ++a) {
                float t = uh[a];
#pragma unroll
                for (int b = 0; b < 6; ++b) t += Ah[a * 6 + b] * xj[b];
                alpha += xi[a] * t;
            }
#pragma unroll
            for (int b = 0; b < 6; ++b) alpha += wh[b] * xj[b];
            alpha *= 0.125f;
            float nm = fmaxf(m, alpha);
            float corr = __expf(m - nm);
            float p = __expf(alpha - nm);
            l = l * corr + p;
#pragma unroll
            for (int a = 0; a < 6; ++a) xh[a] = xh[a] * corr + p * xj[a];
            m = nm;
        }
#pragma unroll
        for (int j = 0; j < 8; ++j) {
            float lb = __shfl(l, j, 64);
            float num = lb * bV[j];
#pragma unroll
            for (int a = 0; a < 6; ++a) num += __shfl(xh[a], j, 64) * wV[j][a];
            float skip = bS[j];
#pragma unroll
            for (int a = 0; a < 6; ++a) skip += xi[a] * wS[j][a];
            float r = num / (lb + 1e-16f) + skip;
            Xout[(size_t)node * DDIM + lane + 64 * j] = f2bf(fmaxf(r, 0.f));
        }
    }
}

// ---------------- main MFMA GEMM (bf16): X[32768,512] @ Wt[2048,512]^T -> Q8/KV8/S16 ----------------
// launch_bounds (256,4): R9 proved (256,5) clamps VGPR to 48 -> acc spills -> 5x traffic. Keep 4.
__global__ __launch_bounds__(256, 4) void k_gemm(const u16* __restrict__ X, const u16* __restrict__ Wt,
                                                 const float* __restrict__ bcat, u8* __restrict__ Q8,
                                                 u8* __restrict__ KV8, u16* __restrict__ S16) {
    __shared__ __align__(16) u16 smem[2 * 128 * 64];  // 32 KB
    u16* As = smem;
    u16* Bs = smem + 128 * 64;
    const int tid = threadIdx.x;
    const int lane = tid & 63;
    const int w = tid >> 6;
    const int wm = w & 1, wn = w >> 1;
    const int bid = blockIdx.x;
    const int xcd = bid & 7;
    const int s = bid >> 3;
    const size_t arow0 = (size_t)(xcd * 32 + (s >> 4)) * 128;
    const size_t brow0 = (size_t)(s & 15) * 128;
    const int bt = (int)(brow0 >> 7);

    f32x4 acc[4][4];
#pragma unroll
    for (int i = 0; i < 4; i++)
#pragma unroll
        for (int j = 0; j < 4; j++) acc[i][j] = (f32x4){0.f, 0.f, 0.f, 0.f};

    const int la = lane & 7;
    const int quad = lane >> 4;
    const int lm = lane & 15;

    for (int kt = 0; kt < 8; ++kt) {
        const int k0 = kt * 64;
#pragma unroll
        for (int t = 0; t < 4; ++t) {
            int idx = (w * 4 + t) * 64 + lane;
            int m = idx >> 3;
            int c = la ^ (m & 7);
            const u16* ga = X + (arow0 + m) * DDIM + (k0 + c * 8);
            const u16* gb = Wt + (brow0 + m) * DDIM + (k0 + c * 8);
            load_lds16(ga, &As[(size_t)((w * 4 + t) * 64) * 8]);
            load_lds16(gb, &Bs[(size_t)((w * 4 + t) * 64) * 8]);
        }
        __syncthreads();
#pragma unroll
        for (int kk = 0; kk < 2; ++kk) {
            bf16x8 af[4], bfg[4];
            int c = kk * 4 + quad;
#pragma unroll
            for (int i = 0; i < 4; ++i) {
                int m = wm * 64 + i * 16 + lm;
                int slot = m * 8 + (c ^ (m & 7));
                af[i] = *(const bf16x8*)&As[(size_t)slot * 8];
            }
#pragma unroll
            for (int j = 0; j < 4; ++j) {
                int n = wn * 64 + j * 16 + lm;
                int slot = n * 8 + (c ^ (n & 7));
                bfg[j] = *(const bf16x8*)&Bs[(size_t)slot * 8];
            }
#pragma unroll
            for (int i = 0; i < 4; ++i)
#pragma unroll
                for (int j = 0; j < 4; ++j)
                    acc[i][j] = __builtin_amdgcn_mfma_f32_16x16x32_bf16(af[i], bfg[j], acc[i][j], 0, 0, 0);
        }
        __syncthreads();
    }

    float biasv[4];
#pragma unroll
    for (int j = 0; j < 4; ++j) biasv[j] = bcat[brow0 + wn * 64 + j * 16 + lm];

    u16* stg = smem;  // [4 waves][32 rows][72 u16]
    const int chunk = lane & 7;
    const int rrow = lane >> 3;
    const int colbase = (int)brow0 + wn * 64 + chunk * 8;
#pragma unroll
    for (int p = 0; p < 2; ++p) {
        __syncthreads();
#pragma unroll
        for (int ii = 0; ii < 2; ++ii) {
            int i = p * 2 + ii;
#pragma unroll
            for (int j = 0; j < 4; ++j) {
#pragma unroll
                for (int r = 0; r < 4; ++r) {
                    int lr = ii * 16 + quad * 4 + r;
                    int lc = j * 16 + lm;
                    stg[(size_t)(w * 32 + lr) * 72 + lc] = f2bf(acc[i][j][r] + biasv[j]);
                }
            }
        }
        __syncthreads();
#pragma unroll
        for (int it = 0; it < 4; ++it) {
            int row = it * 8 + rrow;
            u16x8 v = *(const u16x8*)&stg[(size_t)(w * 32 + row) * 72 + chunk * 8];
            size_t grow = arow0 + wm * 64 + p * 32 + row;
            if (bt < 4) {
                float f[8];
#pragma unroll
                for (int j = 0; j < 8; j++) f[j] = bf2f(v[j]);
                int lo, hi;
                enc8(f, &lo, &hi);
                *(int2*)(Q8 + grow * 512 + colbase) = make_int2(lo, hi);
            } else if (bt < 12) {
                // KV-permuted Wt: logical cols map linearly to KV8 bytes -> contiguous stores, no RMW
                float f[8];
#pragma unroll
                for (int j = 0; j < 8; j++) f[j] = bf2f(v[j]);
                int lo, hi;
                enc8(f, &lo, &hi);
                *(int2*)(KV8 + grow * 1024 + (colbase - 512)) = make_int2(lo, hi);
            } else {
                *(u16x8*)(S16 + grow * 512 + (colbase - 1536)) = v;
            }
        }
    }
}

// ---------------- attention (layers 1-3): one wave per dst node, simple loop (R7-validated) ----------------
__global__ __launch_bounds__(256) void k_attn(const u8* __restrict__ Q8, const u8* __restrict__ KV8,
                                              const u16* __restrict__ S16, const int* __restrict__ offs,
                                              const int* __restrict__ ssrc, u16* __restrict__ Xout) {
    const int lane = threadIdx.x & 63;
    const int node = blockIdx.x * 4 + (threadIdx.x >> 6);
    const u64 q8 = *(const u64*)(Q8 + (size_t)node * 512 + (size_t)lane * 8);
    float qf[8];
    dec8((int)(q8 & 0xFFFFFFFFull), (int)(q8 >> 32), qf);
    float m = -INFINITY, l = 0.f;
    float acc[8];
#pragma unroll
    for (int j = 0; j < 8; j++) acc[j] = 0.f;
    const int e0 = offs[node], e1 = offs[node + 1];
    int4 kvn;
    if (e0 < e1) kvn = *(const int4*)(KV8 + (size_t)ssrc[e0] * 1024 + (size_t)lane * 16);
    for (int e = e0; e < e1; ++e) {
        int4 kv = kvn;
        if (e + 1 < e1) kvn = *(const int4*)(KV8 + (size_t)ssrc[e + 1] * 1024 + (size_t)lane * 16);
        f32x2 k01 = __builtin_amdgcn_cvt_pk_f32_fp8(kv.x, false);
        f32x2 k23 = __builtin_amdgcn_cvt_pk_f32_fp8(kv.x, true);
        f32x2 k45 = __builtin_amdgcn_cvt_pk_f32_fp8(kv.y, false);
        f32x2 k67 = __builtin_amdgcn_cvt_pk_f32_fp8(kv.y, true);
        float d = qf[0] * k01[0] + qf[1] * k01[1] + qf[2] * k23[0] + qf[3] * k23[1] +
                  qf[4] * k45[0] + qf[5] * k45[1] + qf[6] * k67[0] + qf[7] * k67[1];
        d += __shfl_xor(d, 1, 64);
        d += __shfl_xor(d, 2, 64);
        d += __shfl_xor(d, 4, 64);
        float a = d * 0.125f;
        float nm = fmaxf(m, a);
        float corr = __expf(m - nm);
        float p = __expf(a - nm);
        l = l * corr + p;
        f32x2 v01 = __builtin_amdgcn_cvt_pk_f32_fp8(kv.z, false);
        f32x2 v23 = __builtin_amdgcn_cvt_pk_f32_fp8(kv.z, true);
        f32x2 v45 = __builtin_amdgcn_cvt_pk_f32_fp8(kv.w, false);
        f32x2 v67 = __builtin_amdgcn_cvt_pk_f32_fp8(kv.w, true);
        acc[0] = acc[0] * corr + p * v01[0];
        acc[1] = acc[1] * corr + p * v01[1];
        acc[2] = acc[2] * corr + p * v23[0];
        acc[3] = acc[3] * corr + p * v23[1];
        acc[4] = acc[4] * corr + p * v45[0];
        acc[5] = acc[5] * corr + p * v45[1];
        acc[6] = acc[6] * corr + p * v67[0];
        acc[7] = acc[7] * corr + p * v67[1];
        m = nm;
    }
    float inv = 1.0f / (l + 1e-16f);
    const u16x8 sv = *(const u16x8*)(S16 + (size_t)node * 512 + (size_t)lane * 8);
    u16x8 o;
#pragma unroll
    for (int j = 0; j < 8; j++) {
        float r = acc[j] * inv + bf2f(sv[j]);
        o[j] = f2bf(fmaxf(r, 0.f));
    }
    *(u16x8*)(Xout + (size_t)node * DDIM + (size_t)lane * 8) = o;
}

// ---------------- pooling (bf16 input, vectorized) ----------------
__global__ __launch_bounds__(256) void k_pool(const u16* __restrict__ X, float* __restrict__ pooled) {
    __shared__ float red[4][64][8];
    int t = threadIdx.x;
    int chunk = t & 63;
    int rofs = t >> 6;
    float s[8];
#pragma unroll
    for (int j = 0; j < 8; j++) s[j] = 0.f;
    int nd0 = blockIdx.x * 256;
    for (int nd = nd0 + rofs; nd < nd0 + 256; nd += 4) {
        u16x8 v = *(const u16x8*)&X[(size_t)nd * DDIM + chunk * 8];
#pragma unroll
        for (int j = 0; j < 8; j++) s[j] += bf2f(v[j]);
    }
#pragma unroll
    for (int j = 0; j < 8; j++) red[rofs][chunk][j] = s[j];
    __syncthreads();
    if (t < 64) {
#pragma unroll
        for (int j = 0; j < 8; j++) {
            float o = red[0][t][j] + red[1][t][j] + red[2][t][j] + red[3][t][j];
            atomicAdd(&pooled[t * 8 + j], o);
        }
    }
}

// ---------------- heads: emb + hidden layers + critic ----------------
__global__ __launch_bounds__(1024) void k_heads(const float* __restrict__ pooled, const float* __restrict__ fcW,
                                                const float* __restrict__ fcb, const float* __restrict__ ui,
                                                const float* __restrict__ sp, const float* __restrict__ aW1,
                                                const float* __restrict__ ab1, const float* __restrict__ cW1,
                                                const float* __restrict__ cb1, const float* __restrict__ cW2,
                                                const float* __restrict__ cb2, float* __restrict__ hidden_a,
                                                float* __restrict__ out) {
    __shared__ float spool[512];
    __shared__ float semb[64];
    __shared__ float shc[8][128];
    int t = threadIdx.x;
    if (t < 512) spool[t] = pooled[t] * (1.0f / 32768.0f);
    __syncthreads();
    if (t < 64) {
        float s = fcb[t];
        for (int k = 0; k < 512; k++) s += spool[k] * fcW[k * 64 + t];
        semb[t] = s;
    }
    __syncthreads();
    int u = t >> 7, j = t & 127;
    float u0 = ui[u * 2], u1 = ui[u * 2 + 1], uspd = sp[u];
    float ha = ab1[j] + u0 * aW1[j] + u1 * aW1[128 + j] + uspd * aW1[66 * 128 + j];
    float hc = cb1[j] + u0 * cW1[j] + u1 * cW1[128 + j] + uspd * cW1[66 * 128 + j];
    for (int k = 0; k < 64; k++) {
        float e = semb[k];
        ha += e * aW1[(2 + k) * 128 + j];
        hc += e * cW1[(2 + k) * 128 + j];
    }
    ha = fmaxf(ha, 0.f);
    hc = fmaxf(hc, 0.f);
    hidden_a[u * 128 + j] = ha;
    shc[u][j] = hc;
    __syncthreads();
    if (t < 8) {
        float s = cb2[0];
        for (int k = 0; k < 128; k++) s += shc[t][k] * cW2[k];
        out[NNODES + t] = s;
    }
}

// ---------------- actor logits + softmax ----------------
__global__ __launch_bounds__(1024) void k_actor(const float* __restrict__ hidden_a, const float* __restrict__ aW2,
                                                const float* __restrict__ ab2, float* __restrict__ out) {
    __shared__ float h[128];
    __shared__ float red[1024];
    int u = blockIdx.x, t = threadIdx.x;
    if (t < 128) h[t] = hidden_a[u * 128 + t];
    __syncthreads();
    float lg[4];
#pragma unroll
    for (int p = 0; p < 4; p++) {
        int mcol = t + p * 1024;
        float s = ab2[mcol];
        for (int k = 0; k < 128; k++) s += h[k] * aW2[(size_t)k * MM + mcol];
        lg[p] = s;
    }
    float mx = fmaxf(fmaxf(lg[0], lg[1]), fmaxf(lg[2], lg[3]));
    red[t] = mx;
    __syncthreads();
    for (int s2 = 512; s2 > 0; s2 >>= 1) {
        if (t < s2) red[t] = fmaxf(red[t], red[t + s2]);
        __syncthreads();
    }
    mx = red[0];
    __syncthreads();
    float e[4], sum = 0.f;
#pragma unroll
    for (int p = 0; p < 4; p++) {
        e[p] = __expf(lg[p] - mx);
        sum += e[p];
    }
    red[t] = sum;
    __syncthreads();
    for (int s2 = 512; s2 > 0; s2 >>= 1) {
        if (t < s2) red[t] += red[t + s2];
        __syncthreads();
    }
    float inv = 1.0f / red[0];
#pragma unroll
    for (int p = 0; p < 4; p++) out[(size_t)u * MM + t + p * 1024] = e[p] * inv;
}

extern "C" void kernel_launch(void* const* d_in, const int* in_sizes, int n_in,
                              void* d_out, int out_size, void* d_ws, size_t ws_size,
                              hipStream_t stream) {
    const float* mc   = (const float*)d_in[0];
    const float* ui   = (const float*)d_in[1];
    const float* sp   = (const float*)d_in[2];
    const float* cm   = (const float*)d_in[3];
    const float* at   = (const float*)d_in[4];
    const int*   eidx = (const int*)d_in[5];
    const int*   mask = (const int*)d_in[7];
    const float* Wq0 = (const float*)d_in[8];
    const float* bq0 = (const float*)d_in[9];
    const float* Wk0 = (const float*)d_in[10];
    const float* bk0 = (const float*)d_in[11];
    const float* Wv0 = (const float*)d_in[12];
    const float* bv0 = (const float*)d_in[13];
    const float* Ws0 = (const float*)d_in[14];
    const float* bs0 = (const float*)d_in[15];
    const float* Wq = (const float*)d_in[16];
    const float* bq = (const float*)d_in[17];
    const float* Wk = (const float*)d_in[18];
    const float* bk = (const float*)d_in[19];
    const float* Wv = (const float*)d_in[20];
    const float* bv = (const float*)d_in[21];
    const float* Ws = (const float*)d_in[22];
    const float* bs = (const float*)d_in[23];
    const float* fcW = (const float*)d_in[24];
    const float* fcb = (const float*)d_in[25];
    const float* aW1 = (const float*)d_in[26];
    const float* ab1 = (const float*)d_in[27];
    const float* aW2 = (const float*)d_in[28];
    const float* ab2 = (const float*)d_in[29];
    const float* cW1 = (const float*)d_in[30];
    const float* cb1 = (const float*)d_in[31];
    const float* cW2 = (const float*)d_in[32];
    const float* cb2 = (const float*)d_in[33];
    float* out = (float*)d_out;

    const int* esrc = eidx;
    const int* edst = eidx + NEDGES;

    char* ws = (char*)d_ws;
    size_t off = 0;
    auto alloc = [&](size_t bytes) -> void* {
        void* p = ws + off;
        off += (bytes + 255) & ~(size_t)255;
        return p;
    };
    u8*    Q8    = (u8*)alloc((size_t)NNODES * 512);         // 16 MB fp8
    u8*    KV8   = (u8*)alloc((size_t)NNODES * 1024);        // 32 MB fp8 interleaved
    u16*   S16   = (u16*)alloc((size_t)NNODES * 512 * 2);    // 32 MB bf16
    u16*   X     = (u16*)alloc((size_t)NNODES * DDIM * 2);   // 32 MB bf16
    u16*   Wt    = (u16*)alloc((size_t)3 * QK4 * DDIM * 2);  // 6 MB
    float* bcat  = (float*)alloc((size_t)3 * QK4 * 4);
    float* C0    = (float*)alloc((size_t)392 * 4);
    float* x0    = (float*)alloc((size_t)NNODES * 6 * 4);
    int*   deg   = (int*)alloc((size_t)NNODES * 4);
    int*   offs  = (int*)alloc((size_t)(NNODES + 1) * 4);
    int*   cursor= (int*)alloc((size_t)NNODES * 4);
    int*   ssrc  = (int*)alloc((size_t)NEDGES * 4);
    float* pooled= (float*)alloc((size_t)512 * 4);
    float* hidden_a = (float*)alloc((size_t)UU * 128 * 4);
    (void)ws_size; (void)in_sizes; (void)n_in; (void)out_size;

    // prep
    k_prep<<<154, 256, 0, stream>>>(mc, mask, sp, cm, at, x0, bq, bk, bv, bs, bcat, deg, pooled);
    k_c0<<<1, 512, 0, stream>>>(Wq0, bq0, Wk0, bk0, C0);
    {
        dim3 g(16, 16, 12), b(32, 8);
        k_wt<<<g, b, 0, stream>>>(Wq, Wk, Wv, Ws, Wt);
    }
    // CSR
    k_count<<<NEDGES / 256, 256, 0, stream>>>(edst, deg);
    k_scan<<<1, 1024, 0, stream>>>(deg, offs, cursor);
    k_scatter<<<NEDGES / 256, 256, 0, stream>>>(esrc, edst, cursor, ssrc);

    // layer 0: fused 6-dim attention + projection
    k_attn0<<<1024, 256, 0, stream>>>(x0, C0, Wv0, bv0, Ws0, bs0, offs, ssrc, X);

    // layers 1..3
    for (int l = 0; l < 3; ++l) {
        k_gemm<<<4096, 256, 0, stream>>>(X, Wt + (size_t)l * QK4 * DDIM, bcat + (size_t)l * QK4, Q8, KV8, S16);
        k_attn<<<NNODES / 4, 256, 0, stream>>>(Q8, KV8, S16, offs, ssrc, X);
    }

    // pool + heads
    k_pool<<<128, 256, 0, stream>>>(X, pooled);
    k_heads<<<1, 1024, 0, stream>>>(pooled, fcW, fcb, ui, sp, aW1, ab1, cW1, cb1, cW2, cb2, hidden_a, out);
    k_actor<<<UU, 1024, 0, stream>>>(hidden_a, aW2, ab2, out);
}

// Round 11
// 618.533 us; speedup vs baseline: 1.5442x; 1.0334x over previous
//
#include <hip/hip_runtime.h>
#include <stdint.h>

typedef unsigned char u8;
typedef unsigned short u16;
typedef unsigned long long u64;
typedef __attribute__((ext_vector_type(8))) unsigned short u16x8;
typedef __attribute__((ext_vector_type(8))) __bf16 bf16x8;
typedef __attribute__((ext_vector_type(4))) float f32x4;
typedef __attribute__((ext_vector_type(2))) float f32x2;

#define NNODES 32768
#define NEDGES 131072
#define DDIM 512
#define QK4 2048   // 4*DDIM
#define MM 4096
#define UU 8

// Buffers:
//   Q8 [node][512]  fp8
//   KV8[node][1024] fp8, chunk c: K cols c*8..c*8+7 at bytes [c*16,c*16+8), V same cols at [c*16+8,c*16+16)
//   S16[node][512]  bf16
//   X  [node][512]  bf16
// Wt N-order PERMUTED in the KV region so gemm's KV8 stores are linear (R10-validated: WRITE=80MiB exact).

__device__ __forceinline__ u16 f2bf(float f) {
    unsigned u = __builtin_bit_cast(unsigned, f);
    u += 0x7FFFu + ((u >> 16) & 1u);
    return (u16)(u >> 16);
}
__device__ __forceinline__ float bf2f(u16 h) {
    return __builtin_bit_cast(float, (unsigned)h << 16);
}
__device__ __forceinline__ void enc8(const float* f, int* lo, int* hi) {
    int a = __builtin_amdgcn_cvt_pk_fp8_f32(f[0], f[1], 0, false);
    a = __builtin_amdgcn_cvt_pk_fp8_f32(f[2], f[3], a, true);
    int b = __builtin_amdgcn_cvt_pk_fp8_f32(f[4], f[5], 0, false);
    b = __builtin_amdgcn_cvt_pk_fp8_f32(f[6], f[7], b, true);
    *lo = a;
    *hi = b;
}
__device__ __forceinline__ void dec8(int lo, int hi, float* f) {
    f32x2 a = __builtin_amdgcn_cvt_pk_f32_fp8(lo, false);
    f32x2 b = __builtin_amdgcn_cvt_pk_f32_fp8(lo, true);
    f32x2 c = __builtin_amdgcn_cvt_pk_f32_fp8(hi, false);
    f32x2 d = __builtin_amdgcn_cvt_pk_f32_fp8(hi, true);
    f[0] = a[0]; f[1] = a[1]; f[2] = b[0]; f[3] = b[1];
    f[4] = c[0]; f[5] = c[1]; f[6] = d[0]; f[7] = d[1];
}

__device__ __forceinline__ void load_lds16(const void* g, void* l) {
    __builtin_amdgcn_global_load_lds((__attribute__((address_space(1))) unsigned int*)(void*)g,
                                     (__attribute__((address_space(3))) unsigned int*)l, 16, 0, 0);
}

// ---------------- fused prep: deg-zero + pooled-zero + x0 + bcat (KV-permuted) ----------------
__global__ void k_prep(const float* __restrict__ mc, const int* __restrict__ mask,
                       const float* __restrict__ sp, const float* __restrict__ cm,
                       const float* __restrict__ at, float* __restrict__ x0,
                       const float* __restrict__ bq, const float* __restrict__ bk,
                       const float* __restrict__ bv, const float* __restrict__ bs,
                       float* __restrict__ bcat,
                       int* __restrict__ deg, float* __restrict__ pooled) {
    int b = blockIdx.x;
    int t = threadIdx.x;
    if (b < 128) {
        int node = b * 256 + t;
        deg[node] = 0;
        int m = node >> 3, u = node & 7;
        float* o = x0 + (size_t)node * 6;
        o[0] = mc[m * 2];
        o[1] = mc[m * 2 + 1];
        o[2] = (float)mask[m];
        o[3] = sp[u];
        o[4] = cm[u * MM + m];
        o[5] = at[u * MM + m];
    } else if (b < 152) {
        int i = (b - 128) * 256 + t;
        int n = i & (QK4 - 1);
        int l = i >> 11;
        const float* p;
        int col;
        if (n < 512) { p = bq; col = n; }
        else if (n < 1536) {
            int g = n - 512, c = g >> 4, r = g & 15;
            if (r < 8) { p = bk; col = c * 8 + r; }
            else { p = bv; col = c * 8 + r - 8; }
        } else { p = bs; col = n - 1536; }
        bcat[(size_t)l * QK4 + n] = p[l * DDIM + col];
    } else {
        pooled[(b - 152) * 256 + t] = 0.f;
    }
}

// ---------------- layer-0 attention constants ----------------
__global__ void k_c0(const float* __restrict__ Wq0, const float* __restrict__ bq0,
                     const float* __restrict__ Wk0, const float* __restrict__ bk0,
                     float* __restrict__ C0) {
    int i = threadIdx.x;
    if (i >= 392) return;
    int h = i / 49, r = i % 49;
    int d0 = h * 64;
    float s = 0.f;
    if (r < 36) {
        int a = r / 6, b = r % 6;
        for (int d = 0; d < 64; d++) s += Wq0[a * DDIM + d0 + d] * Wk0[b * DDIM + d0 + d];
    } else if (r < 42) {
        int a = r - 36;
        for (int d = 0; d < 64; d++) s += Wq0[a * DDIM + d0 + d] * bk0[d0 + d];
    } else if (r < 48) {
        int b = r - 42;
        for (int d = 0; d < 64; d++) s += Wk0[b * DDIM + d0 + d] * bq0[d0 + d];
    } else {
        for (int d = 0; d < 64; d++) s += bq0[d0 + d] * bk0[d0 + d];
    }
    C0[i] = s;
}

// transpose [512][512] fp32 into Wt[layer][2048][512] bf16, KV rows interleaved
__global__ void k_wt(const float* __restrict__ Wq, const float* __restrict__ Wk,
                     const float* __restrict__ Wv, const float* __restrict__ Ws,
                     u16* __restrict__ Wt) {
    __shared__ float tile[32][33];
    int q = blockIdx.z;
    int l = q >> 2, t = q & 3;
    const float* src = ((t == 0) ? Wq : (t == 1) ? Wk : (t == 2) ? Wv : Ws) + (size_t)l * DDIM * DDIM;
    int k0 = blockIdx.x * 32, n0 = blockIdx.y * 32;
    int tx = threadIdx.x, ty = threadIdx.y;
#pragma unroll
    for (int r = 0; r < 4; r++) tile[ty + 8 * r][tx] = src[(size_t)(k0 + ty + 8 * r) * DDIM + n0 + tx];
    __syncthreads();
    u16* dst = Wt + (size_t)l * QK4 * DDIM;
#pragma unroll
    for (int r = 0; r < 4; r++) {
        int nn = n0 + ty + 8 * r;
        int n;
        if (t == 0) n = nn;
        else if (t == 1) n = 512 + ((nn >> 3) << 4) + (nn & 7);
        else if (t == 2) n = 512 + ((nn >> 3) << 4) + 8 + (nn & 7);
        else n = 1536 + nn;
        dst[(size_t)n * DDIM + k0 + tx] = f2bf(tile[tx][ty + 8 * r]);
    }
}

// ---------------- CSR build ----------------
__global__ void k_count(const int* __restrict__ dst, int* __restrict__ deg) {
    int e = blockIdx.x * 256 + threadIdx.x;
    if (e < NEDGES) atomicAdd(&deg[dst[e]], 1);
}

__global__ __launch_bounds__(1024) void k_scan(const int* __restrict__ deg, int* __restrict__ offs,
                                               int* __restrict__ cursor) {
    __shared__ int sums[1024];
    int t = threadIdx.x;
    int base = t * 32;
    int local[32];
    int s = 0;
#pragma unroll
    for (int i = 0; i < 32; i++) { local[i] = s; s += deg[base + i]; }
    sums[t] = s;
    __syncthreads();
    for (int d = 1; d < 1024; d <<= 1) {
        int v = (t >= d) ? sums[t - d] : 0;
        __syncthreads();
        sums[t] += v;
        __syncthreads();
    }
    int excl = (t == 0) ? 0 : sums[t - 1];
#pragma unroll
    for (int i = 0; i < 32; i++) {
        int o = excl + local[i];
        offs[base + i] = o;
        cursor[base + i] = o;
    }
    if (t == 1023) offs[NNODES] = sums[1023];
}

__global__ void k_scatter(const int* __restrict__ src, const int* __restrict__ dst,
                          int* __restrict__ cursor, int* __restrict__ ssrc) {
    int e = blockIdx.x * 256 + threadIdx.x;
    if (e < NEDGES) {
        int pos = atomicAdd(&cursor[dst[e]], 1);
        ssrc[pos] = src[e];
    }
}

// ---------------- fused layer-0 conv: 6-dim attention + projection -> X bf16 ----------------
__global__ __launch_bounds__(256) void k_attn0(const float* __restrict__ x0, const float* __restrict__ C0,
                                               const float* __restrict__ Wv0, const float* __restrict__ bv0,
                                               const float* __restrict__ Ws0, const float* __restrict__ bs0,
                                               const int* __restrict__ offs, const int* __restrict__ ssrc,
                                               u16* __restrict__ Xout) {
    const int lane = threadIdx.x & 63;
    const int wv = threadIdx.x >> 6;
    const int h = lane & 7;
    float wV[8][6], wS[8][6], bV[8], bS[8];
#pragma unroll
    for (int j = 0; j < 8; ++j) {
        int c = lane + 64 * j;
        bV[j] = bv0[c];
        bS[j] = bs0[c];
#pragma unroll
        for (int a = 0; a < 6; ++a) {
            wV[j][a] = Wv0[a * DDIM + c];
            wS[j][a] = Ws0[a * DDIM + c];
        }
    }
    float Ah[36], uh[6], wh[6], ch;
#pragma unroll
    for (int r = 0; r < 36; ++r) Ah[r] = C0[h * 49 + r];
#pragma unroll
    for (int a = 0; a < 6; ++a) uh[a] = C0[h * 49 + 36 + a];
#pragma unroll
    for (int a = 0; a < 6; ++a) wh[a] = C0[h * 49 + 42 + a];
    ch = C0[h * 49 + 48];

    int node0 = (blockIdx.x * 4 + wv) * 8;
    for (int nn = 0; nn < 8; ++nn) {
        int node = node0 + nn;
        float xi[6];
#pragma unroll
        for (int a = 0; a < 6; ++a) xi[a] = x0[(size_t)node * 6 + a];
        float m = -INFINITY, l = 0.f;
        float xh[6];
#pragma unroll
        for (int a = 0; a < 6; ++a) xh[a] = 0.f;
        const int e0 = offs[node], e1 = offs[node + 1];
        for (int e = e0; e < e1; ++e) {
            int s = ssrc[e];
            float xj[6];
#pragma unroll
            for (int a = 0; a < 6; ++a) xj[a] = x0[(size_t)s * 6 + a];
            float alpha = ch;
#pragma unroll
            for (int a = 0; a < 6; ++a) {
                float t = uh[a];
#pragma unroll
                for (int b = 0; b < 6; ++b) t += Ah[a * 6 + b] * xj[b];
                alpha += xi[a] * t;
            }
#pragma unroll
            for (int b = 0; b < 6; ++b) alpha += wh[b] * xj[b];
            alpha *= 0.125f;
            float nm = fmaxf(m, alpha);
            float corr = __expf(m - nm);
            float p = __expf(alpha - nm);
            l = l * corr + p;
#pragma unroll
            for (int a = 0; a < 6; ++a) xh[a] = xh[a] * corr + p * xj[a];
            m = nm;
        }
#pragma unroll
        for (int j = 0; j < 8; ++j) {
            float lb = __shfl(l, j, 64);
            float num = lb * bV[j];
#pragma unroll
            for (int a = 0; a < 6; ++a) num += __shfl(xh[a], j, 64) * wV[j][a];
            float skip = bS[j];
#pragma unroll
            for (int a = 0; a < 6; ++a) skip += xi[a] * wS[j][a];
            float r = num / (lb + 1e-16f) + skip;
            Xout[(size_t)node * DDIM + lane + 64 * j] = f2bf(fmaxf(r, 0.f));
        }
    }
}

// ---------------- main MFMA GEMM (bf16): X[32768,512] @ Wt[2048,512]^T -> Q8/KV8/S16 ----------------
// (256,4): R9 proved (256,5) clamps VGPR to 48 -> spill -> 5x traffic. Keep 4.
__global__ __launch_bounds__(256, 4) void k_gemm(const u16* __restrict__ X, const u16* __restrict__ Wt,
                                                 const float* __restrict__ bcat, u8* __restrict__ Q8,
                                                 u8* __restrict__ KV8, u16* __restrict__ S16) {
    __shared__ __align__(16) u16 smem[2 * 128 * 64];  // 32 KB
    u16* As = smem;
    u16* Bs = smem + 128 * 64;
    const int tid = threadIdx.x;
    const int lane = tid & 63;
    const int w = tid >> 6;
    const int wm = w & 1, wn = w >> 1;
    const int bid = blockIdx.x;
    const int xcd = bid & 7;
    const int s = bid >> 3;
    const size_t arow0 = (size_t)(xcd * 32 + (s >> 4)) * 128;
    const size_t brow0 = (size_t)(s & 15) * 128;
    const int bt = (int)(brow0 >> 7);

    f32x4 acc[4][4];
#pragma unroll
    for (int i = 0; i < 4; i++)
#pragma unroll
        for (int j = 0; j < 4; j++) acc[i][j] = (f32x4){0.f, 0.f, 0.f, 0.f};

    const int la = lane & 7;
    const int quad = lane >> 4;
    const int lm = lane & 15;

    for (int kt = 0; kt < 8; ++kt) {
        const int k0 = kt * 64;
#pragma unroll
        for (int t = 0; t < 4; ++t) {
            int idx = (w * 4 + t) * 64 + lane;
            int m = idx >> 3;
            int c = la ^ (m & 7);
            const u16* ga = X + (arow0 + m) * DDIM + (k0 + c * 8);
            const u16* gb = Wt + (brow0 + m) * DDIM + (k0 + c * 8);
            load_lds16(ga, &As[(size_t)((w * 4 + t) * 64) * 8]);
            load_lds16(gb, &Bs[(size_t)((w * 4 + t) * 64) * 8]);
        }
        __syncthreads();
#pragma unroll
        for (int kk = 0; kk < 2; ++kk) {
            bf16x8 af[4], bfg[4];
            int c = kk * 4 + quad;
#pragma unroll
            for (int i = 0; i < 4; ++i) {
                int m = wm * 64 + i * 16 + lm;
                int slot = m * 8 + (c ^ (m & 7));
                af[i] = *(const bf16x8*)&As[(size_t)slot * 8];
            }
#pragma unroll
            for (int j = 0; j < 4; ++j) {
                int n = wn * 64 + j * 16 + lm;
                int slot = n * 8 + (c ^ (n & 7));
                bfg[j] = *(const bf16x8*)&Bs[(size_t)slot * 8];
            }
#pragma unroll
            for (int i = 0; i < 4; ++i)
#pragma unroll
                for (int j = 0; j < 4; ++j)
                    acc[i][j] = __builtin_amdgcn_mfma_f32_16x16x32_bf16(af[i], bfg[j], acc[i][j], 0, 0, 0);
        }
        __syncthreads();
    }

    float biasv[4];
#pragma unroll
    for (int j = 0; j < 4; ++j) biasv[j] = bcat[brow0 + wn * 64 + j * 16 + lm];

    u16* stg = smem;  // [4 waves][32 rows][72 u16]
    const int chunk = lane & 7;
    const int rrow = lane >> 3;
    const int colbase = (int)brow0 + wn * 64 + chunk * 8;
#pragma unroll
    for (int p = 0; p < 2; ++p) {
        __syncthreads();
#pragma unroll
        for (int ii = 0; ii < 2; ++ii) {
            int i = p * 2 + ii;
#pragma unroll
            for (int j = 0; j < 4; ++j) {
#pragma unroll
                for (int r = 0; r < 4; ++r) {
                    int lr = ii * 16 + quad * 4 + r;
                    int lc = j * 16 + lm;
                    stg[(size_t)(w * 32 + lr) * 72 + lc] = f2bf(acc[i][j][r] + biasv[j]);
                }
            }
        }
        __syncthreads();
#pragma unroll
        for (int it = 0; it < 4; ++it) {
            int row = it * 8 + rrow;
            u16x8 v = *(const u16x8*)&stg[(size_t)(w * 32 + row) * 72 + chunk * 8];
            size_t grow = arow0 + wm * 64 + p * 32 + row;
            if (bt < 4) {
                float f[8];
#pragma unroll
                for (int j = 0; j < 8; j++) f[j] = bf2f(v[j]);
                int lo, hi;
                enc8(f, &lo, &hi);
                *(int2*)(Q8 + grow * 512 + colbase) = make_int2(lo, hi);
            } else if (bt < 12) {
                float f[8];
#pragma unroll
                for (int j = 0; j < 8; j++) f[j] = bf2f(v[j]);
                int lo, hi;
                enc8(f, &lo, &hi);
                *(int2*)(KV8 + grow * 1024 + (colbase - 512)) = make_int2(lo, hi);
            } else {
                *(u16x8*)(S16 + grow * 512 + (colbase - 1536)) = v;
            }
        }
    }
}

// ---------------- attention (layers 1-3): one wave per dst node, 4-deep KV batch (R8-validated) ----------------
__global__ __launch_bounds__(256) void k_attn(const u8* __restrict__ Q8, const u8* __restrict__ KV8,
                                              const u16* __restrict__ S16, const int* __restrict__ offs,
                                              const int* __restrict__ ssrc, u16* __restrict__ Xout) {
    const int lane = threadIdx.x & 63;
    const int node = blockIdx.x * 4 + (threadIdx.x >> 6);
    const u64 q8 = *(const u64*)(Q8 + (size_t)node * 512 + (size_t)lane * 8);
    const u16x8 sv = *(const u16x8*)(S16 + (size_t)node * 512 + (size_t)lane * 8);  // hoisted: independent
    float qf[8];
    dec8((int)(q8 & 0xFFFFFFFFull), (int)(q8 >> 32), qf);
    float m = -INFINITY, l = 0.f;
    float acc[8];
#pragma unroll
    for (int j = 0; j < 8; j++) acc[j] = 0.f;
    const int e0 = offs[node], e1 = offs[node + 1];
    int e = e0;
    while (e < e1) {
        int nb = e1 - e;
        if (nb > 4) nb = 4;
        int4 kvb[4];
#pragma unroll
        for (int i = 0; i < 4; ++i) {
            if (i < nb) {
                int s = ssrc[e + i];
                kvb[i] = *(const int4*)(KV8 + (size_t)s * 1024 + (size_t)lane * 16);
            }
        }
#pragma unroll
        for (int i = 0; i < 4; ++i) {
            if (i >= nb) break;
            int4 kv = kvb[i];
            f32x2 k01 = __builtin_amdgcn_cvt_pk_f32_fp8(kv.x, false);
            f32x2 k23 = __builtin_amdgcn_cvt_pk_f32_fp8(kv.x, true);
            f32x2 k45 = __builtin_amdgcn_cvt_pk_f32_fp8(kv.y, false);
            f32x2 k67 = __builtin_amdgcn_cvt_pk_f32_fp8(kv.y, true);
            float d = qf[0] * k01[0] + qf[1] * k01[1] + qf[2] * k23[0] + qf[3] * k23[1] +
                      qf[4] * k45[0] + qf[5] * k45[1] + qf[6] * k67[0] + qf[7] * k67[1];
            d += __shfl_xor(d, 1, 64);
            d += __shfl_xor(d, 2, 64);
            d += __shfl_xor(d, 4, 64);
            float a = d * 0.125f;
            float nm = fmaxf(m, a);
            float corr = __expf(m - nm);
            float p = __expf(a - nm);
            l = l * corr + p;
            f32x2 v01 = __builtin_amdgcn_cvt_pk_f32_fp8(kv.z, false);
            f32x2 v23 = __builtin_amdgcn_cvt_pk_f32_fp8(kv.z, true);
            f32x2 v45 = __builtin_amdgcn_cvt_pk_f32_fp8(kv.w, false);
            f32x2 v67 = __builtin_amdgcn_cvt_pk_f32_fp8(kv.w, true);
            acc[0] = acc[0] * corr + p * v01[0];
            acc[1] = acc[1] * corr + p * v01[1];
            acc[2] = acc[2] * corr + p * v23[0];
            acc[3] = acc[3] * corr + p * v23[1];
            acc[4] = acc[4] * corr + p * v45[0];
            acc[5] = acc[5] * corr + p * v45[1];
            acc[6] = acc[6] * corr + p * v67[0];
            acc[7] = acc[7] * corr + p * v67[1];
            m = nm;
        }
        e += nb;
    }
    float inv = 1.0f / (l + 1e-16f);
    u16x8 o;
#pragma unroll
    for (int j = 0; j < 8; j++) {
        float r = acc[j] * inv + bf2f(sv[j]);
        o[j] = f2bf(fmaxf(r, 0.f));
    }
    *(u16x8*)(Xout + (size_t)node * DDIM + (size_t)lane * 8) = o;
}

// ---------------- pooling (bf16 input, vectorized) ----------------
__global__ __launch_bounds__(256) void k_pool(const u16* __restrict__ X, float* __restrict__ pooled) {
    __shared__ float red[4][64][8];
    int t = threadIdx.x;
    int chunk = t & 63;
    int rofs = t >> 6;
    float s[8];
#pragma unroll
    for (int j = 0; j < 8; j++) s[j] = 0.f;
    int nd0 = blockIdx.x * 256;
    for (int nd = nd0 + rofs; nd < nd0 + 256; nd += 4) {
        u16x8 v = *(const u16x8*)&X[(size_t)nd * DDIM + chunk * 8];
#pragma unroll
        for (int j = 0; j < 8; j++) s[j] += bf2f(v[j]);
    }
#pragma unroll
    for (int j = 0; j < 8; j++) red[rofs][chunk][j] = s[j];
    __syncthreads();
    if (t < 64) {
#pragma unroll
        for (int j = 0; j < 8; j++) {
            float o = red[0][t][j] + red[1][t][j] + red[2][t][j] + red[3][t][j];
            atomicAdd(&pooled[t * 8 + j], o);
        }
    }
}

// ---------------- heads: emb + hidden layers + critic ----------------
__global__ __launch_bounds__(1024) void k_heads(const float* __restrict__ pooled, const float* __restrict__ fcW,
                                                const float* __restrict__ fcb, const float* __restrict__ ui,
                                                const float* __restrict__ sp, const float* __restrict__ aW1,
                                                const float* __restrict__ ab1, const float* __restrict__ cW1,
                                                const float* __restrict__ cb1, const float* __restrict__ cW2,
                                                const float* __restrict__ cb2, float* __restrict__ hidden_a,
                                                float* __restrict__ out) {
    __shared__ float spool[512];
    __shared__ float semb[64];
    __shared__ float shc[8][128];
    int t = threadIdx.x;
    if (t < 512) spool[t] = pooled[t] * (1.0f / 32768.0f);
    __syncthreads();
    if (t < 64) {
        float s = fcb[t];
        for (int k = 0; k < 512; k++) s += spool[k] * fcW[k * 64 + t];
        semb[t] = s;
    }
    __syncthreads();
    int u = t >> 7, j = t & 127;
    float u0 = ui[u * 2], u1 = ui[u * 2 + 1], uspd = sp[u];
    float ha = ab1[j] + u0 * aW1[j] + u1 * aW1[128 + j] + uspd * aW1[66 * 128 + j];
    float hc = cb1[j] + u0 * cW1[j] + u1 * cW1[128 + j] + uspd * cW1[66 * 128 + j];
    for (int k = 0; k < 64; k++) {
        float e = semb[k];
        ha += e * aW1[(2 + k) * 128 + j];
        hc += e * cW1[(2 + k) * 128 + j];
    }
    ha = fmaxf(ha, 0.f);
    hc = fmaxf(hc, 0.f);
    hidden_a[u * 128 + j] = ha;
    shc[u][j] = hc;
    __syncthreads();
    if (t < 8) {
        float s = cb2[0];
        for (int k = 0; k < 128; k++) s += shc[t][k] * cW2[k];
        out[NNODES + t] = s;
    }
}

// ---------------- actor logits + softmax ----------------
__global__ __launch_bounds__(1024) void k_actor(const float* __restrict__ hidden_a, const float* __restrict__ aW2,
                                                const float* __restrict__ ab2, float* __restrict__ out) {
    __shared__ float h[128];
    __shared__ float red[1024];
    int u = blockIdx.x, t = threadIdx.x;
    if (t < 128) h[t] = hidden_a[u * 128 + t];
    __syncthreads();
    float lg[4];
#pragma unroll
    for (int p = 0; p < 4; p++) {
        int mcol = t + p * 1024;
        float s = ab2[mcol];
        for (int k = 0; k < 128; k++) s += h[k] * aW2[(size_t)k * MM + mcol];
        lg[p] = s;
    }
    float mx = fmaxf(fmaxf(lg[0], lg[1]), fmaxf(lg[2], lg[3]));
    red[t] = mx;
    __syncthreads();
    for (int s2 = 512; s2 > 0; s2 >>= 1) {
        if (t < s2) red[t] = fmaxf(red[t], red[t + s2]);
        __syncthreads();
    }
    mx = red[0];
    __syncthreads();
    float e[4], sum = 0.f;
#pragma unroll
    for (int p = 0; p < 4; p++) {
        e[p] = __expf(lg[p] - mx);
        sum += e[p];
    }
    red[t] = sum;
    __syncthreads();
    for (int s2 = 512; s2 > 0; s2 >>= 1) {
        if (t < s2) red[t] += red[t + s2];
        __syncthreads();
    }
    float inv = 1.0f / red[0];
#pragma unroll
    for (int p = 0; p < 4; p++) out[(size_t)u * MM + t + p * 1024] = e[p] * inv;
}

extern "C" void kernel_launch(void* const* d_in, const int* in_sizes, int n_in,
                              void* d_out, int out_size, void* d_ws, size_t ws_size,
                              hipStream_t stream) {
    const float* mc   = (const float*)d_in[0];
    const float* ui   = (const float*)d_in[1];
    const float* sp   = (const float*)d_in[2];
    const float* cm   = (const float*)d_in[3];
    const float* at   = (const float*)d_in[4];
    const int*   eidx = (const int*)d_in[5];
    const int*   mask = (const int*)d_in[7];
    const float* Wq0 = (const float*)d_in[8];
    const float* bq0 = (const float*)d_in[9];
    const float* Wk0 = (const float*)d_in[10];
    const float* bk0 = (const float*)d_in[11];
    const float* Wv0 = (const float*)d_in[12];
    const float* bv0 = (const float*)d_in[13];
    const float* Ws0 = (const float*)d_in[14];
    const float* bs0 = (const float*)d_in[15];
    const float* Wq = (const float*)d_in[16];
    const float* bq = (const float*)d_in[17];
    const float* Wk = (const float*)d_in[18];
    const float* bk = (const float*)d_in[19];
    const float* Wv = (const float*)d_in[20];
    const float* bv = (const float*)d_in[21];
    const float* Ws = (const float*)d_in[22];
    const float* bs = (const float*)d_in[23];
    const float* fcW = (const float*)d_in[24];
    const float* fcb = (const float*)d_in[25];
    const float* aW1 = (const float*)d_in[26];
    const float* ab1 = (const float*)d_in[27];
    const float* aW2 = (const float*)d_in[28];
    const float* ab2 = (const float*)d_in[29];
    const float* cW1 = (const float*)d_in[30];
    const float* cb1 = (const float*)d_in[31];
    const float* cW2 = (const float*)d_in[32];
    const float* cb2 = (const float*)d_in[33];
    float* out = (float*)d_out;

    const int* esrc = eidx;
    const int* edst = eidx + NEDGES;

    char* ws = (char*)d_ws;
    size_t off = 0;
    auto alloc = [&](size_t bytes) -> void* {
        void* p = ws + off;
        off += (bytes + 255) & ~(size_t)255;
        return p;
    };
    u8*    Q8    = (u8*)alloc((size_t)NNODES * 512);         // 16 MB fp8
    u8*    KV8   = (u8*)alloc((size_t)NNODES * 1024);        // 32 MB fp8 interleaved
    u16*   S16   = (u16*)alloc((size_t)NNODES * 512 * 2);    // 32 MB bf16
    u16*   X     = (u16*)alloc((size_t)NNODES * DDIM * 2);   // 32 MB bf16
    u16*   Wt    = (u16*)alloc((size_t)3 * QK4 * DDIM * 2);  // 6 MB
    float* bcat  = (float*)alloc((size_t)3 * QK4 * 4);
    float* C0    = (float*)alloc((size_t)392 * 4);
    float* x0    = (float*)alloc((size_t)NNODES * 6 * 4);
    int*   deg   = (int*)alloc((size_t)NNODES * 4);
    int*   offs  = (int*)alloc((size_t)(NNODES + 1) * 4);
    int*   cursor= (int*)alloc((size_t)NNODES * 4);
    int*   ssrc  = (int*)alloc((size_t)NEDGES * 4);
    float* pooled= (float*)alloc((size_t)512 * 4);
    float* hidden_a = (float*)alloc((size_t)UU * 128 * 4);
    (void)ws_size; (void)in_sizes; (void)n_in; (void)out_size;

    // prep
    k_prep<<<154, 256, 0, stream>>>(mc, mask, sp, cm, at, x0, bq, bk, bv, bs, bcat, deg, pooled);
    k_c0<<<1, 512, 0, stream>>>(Wq0, bq0, Wk0, bk0, C0);
    {
        dim3 g(16, 16, 12), b(32, 8);
        k_wt<<<g, b, 0, stream>>>(Wq, Wk, Wv, Ws, Wt);
    }
    // CSR
    k_count<<<NEDGES / 256, 256, 0, stream>>>(edst, deg);
    k_scan<<<1, 1024, 0, stream>>>(deg, offs, cursor);
    k_scatter<<<NEDGES / 256, 256, 0, stream>>>(esrc, edst, cursor, ssrc);

    // layer 0: fused 6-dim attention + projection
    k_attn0<<<1024, 256, 0, stream>>>(x0, C0, Wv0, bv0, Ws0, bs0, offs, ssrc, X);

    // layers 1..3
    for (int l = 0; l < 3; ++l) {
        k_gemm<<<4096, 256, 0, stream>>>(X, Wt + (size_t)l * QK4 * DDIM, bcat + (size_t)l * QK4, Q8, KV8, S16);
        k_attn<<<NNODES / 4, 256, 0, stream>>>(Q8, KV8, S16, offs, ssrc, X);
    }

    // pool + heads
    k_pool<<<128, 256, 0, stream>>>(X, pooled);
    k_heads<<<1, 1024, 0, stream>>>(pooled, fcW, fcb, ui, sp, aW1, ab1, cW1, cb1, cW2, cb2, hidden_a, out);
    k_actor<<<UU, 1024, 0, stream>>>(hidden_a, aW2, ab2, out);
}

// Round 12
// 592.739 us; speedup vs baseline: 1.6114x; 1.0435x over previous
//
#include <hip/hip_runtime.h>
#include <stdint.h>

typedef unsigned char u8;
typedef unsigned short u16;
typedef unsigned long long u64;
typedef __attribute__((ext_vector_type(8))) unsigned short u16x8;
typedef __attribute__((ext_vector_type(8))) __bf16 bf16x8;
typedef __attribute__((ext_vector_type(4))) float f32x4;
typedef __attribute__((ext_vector_type(2))) float f32x2;

#define NNODES 32768
#define NEDGES 131072
#define DDIM 512
#define QK4 2048   // 4*DDIM
#define MM 4096
#define UU 8

// Buffers:
//   Q8 [node][512]  fp8
//   KV8[node][1024] fp8, chunk c: K cols c*8..c*8+7 at bytes [c*16,c*16+8), V same cols at [c*16+8,c*16+16)
//   S16[node][512]  bf16
//   X  [node][512]  bf16
// Wt N-order PERMUTED in the KV region so gemm's KV8 stores are linear (R10-validated: WRITE=80MiB exact).

__device__ __forceinline__ u16 f2bf(float f) {
    unsigned u = __builtin_bit_cast(unsigned, f);
    u += 0x7FFFu + ((u >> 16) & 1u);
    return (u16)(u >> 16);
}
__device__ __forceinline__ float bf2f(u16 h) {
    return __builtin_bit_cast(float, (unsigned)h << 16);
}
__device__ __forceinline__ void enc8(const float* f, int* lo, int* hi) {
    int a = __builtin_amdgcn_cvt_pk_fp8_f32(f[0], f[1], 0, false);
    a = __builtin_amdgcn_cvt_pk_fp8_f32(f[2], f[3], a, true);
    int b = __builtin_amdgcn_cvt_pk_fp8_f32(f[4], f[5], 0, false);
    b = __builtin_amdgcn_cvt_pk_fp8_f32(f[6], f[7], b, true);
    *lo = a;
    *hi = b;
}
__device__ __forceinline__ void dec8(int lo, int hi, float* f) {
    f32x2 a = __builtin_amdgcn_cvt_pk_f32_fp8(lo, false);
    f32x2 b = __builtin_amdgcn_cvt_pk_f32_fp8(lo, true);
    f32x2 c = __builtin_amdgcn_cvt_pk_f32_fp8(hi, false);
    f32x2 d = __builtin_amdgcn_cvt_pk_f32_fp8(hi, true);
    f[0] = a[0]; f[1] = a[1]; f[2] = b[0]; f[3] = b[1];
    f[4] = c[0]; f[5] = c[1]; f[6] = d[0]; f[7] = d[1];
}

__device__ __forceinline__ void load_lds16(const void* g, void* l) {
    __builtin_amdgcn_global_load_lds((__attribute__((address_space(1))) unsigned int*)(void*)g,
                                     (__attribute__((address_space(3))) unsigned int*)l, 16, 0, 0);
}

// ---------------- fused prep: deg-zero + pooled-zero + x0 + bcat (KV-permuted) ----------------
__global__ void k_prep(const float* __restrict__ mc, const int* __restrict__ mask,
                       const float* __restrict__ sp, const float* __restrict__ cm,
                       const float* __restrict__ at, float* __restrict__ x0,
                       const float* __restrict__ bq, const float* __restrict__ bk,
                       const float* __restrict__ bv, const float* __restrict__ bs,
                       float* __restrict__ bcat,
                       int* __restrict__ deg, float* __restrict__ pooled) {
    int b = blockIdx.x;
    int t = threadIdx.x;
    if (b < 128) {
        int node = b * 256 + t;
        deg[node] = 0;
        int m = node >> 3, u = node & 7;
        float* o = x0 + (size_t)node * 6;
        o[0] = mc[m * 2];
        o[1] = mc[m * 2 + 1];
        o[2] = (float)mask[m];
        o[3] = sp[u];
        o[4] = cm[u * MM + m];
        o[5] = at[u * MM + m];
    } else if (b < 152) {
        int i = (b - 128) * 256 + t;
        int n = i & (QK4 - 1);
        int l = i >> 11;
        const float* p;
        int col;
        if (n < 512) { p = bq; col = n; }
        else if (n < 1536) {
            int g = n - 512, c = g >> 4, r = g & 15;
            if (r < 8) { p = bk; col = c * 8 + r; }
            else { p = bv; col = c * 8 + r - 8; }
        } else { p = bs; col = n - 1536; }
        bcat[(size_t)l * QK4 + n] = p[l * DDIM + col];
    } else {
        pooled[(b - 152) * 256 + t] = 0.f;
    }
}

// ---------------- layer-0 attention constants ----------------
__global__ void k_c0(const float* __restrict__ Wq0, const float* __restrict__ bq0,
                     const float* __restrict__ Wk0, const float* __restrict__ bk0,
                     float* __restrict__ C0) {
    int i = threadIdx.x;
    if (i >= 392) return;
    int h = i / 49, r = i % 49;
    int d0 = h * 64;
    float s = 0.f;
    if (r < 36) {
        int a = r / 6, b = r % 6;
        for (int d = 0; d < 64; d++) s += Wq0[a * DDIM + d0 + d] * Wk0[b * DDIM + d0 + d];
    } else if (r < 42) {
        int a = r - 36;
        for (int d = 0; d < 64; d++) s += Wq0[a * DDIM + d0 + d] * bk0[d0 + d];
    } else if (r < 48) {
        int b = r - 42;
        for (int d = 0; d < 64; d++) s += Wk0[b * DDIM + d0 + d] * bq0[d0 + d];
    } else {
        for (int d = 0; d < 64; d++) s += bq0[d0 + d] * bk0[d0 + d];
    }
    C0[i] = s;
}

// transpose [512][512] fp32 into Wt[layer][2048][512] bf16, KV rows interleaved
__global__ void k_wt(const float* __restrict__ Wq, const float* __restrict__ Wk,
                     const float* __restrict__ Wv, const float* __restrict__ Ws,
                     u16* __restrict__ Wt) {
    __shared__ float tile[32][33];
    int q = blockIdx.z;
    int l = q >> 2, t = q & 3;
    const float* src = ((t == 0) ? Wq : (t == 1) ? Wk : (t == 2) ? Wv : Ws) + (size_t)l * DDIM * DDIM;
    int k0 = blockIdx.x * 32, n0 = blockIdx.y * 32;
    int tx = threadIdx.x, ty = threadIdx.y;
#pragma unroll
    for (int r = 0; r < 4; r++) tile[ty + 8 * r][tx] = src[(size_t)(k0 + ty + 8 * r) * DDIM + n0 + tx];
    __syncthreads();
    u16* dst = Wt + (size_t)l * QK4 * DDIM;
#pragma unroll
    for (int r = 0; r < 4; r++) {
        int nn = n0 + ty + 8 * r;
        int n;
        if (t == 0) n = nn;
        else if (t == 1) n = 512 + ((nn >> 3) << 4) + (nn & 7);
        else if (t == 2) n = 512 + ((nn >> 3) << 4) + 8 + (nn & 7);
        else n = 1536 + nn;
        dst[(size_t)n * DDIM + k0 + tx] = f2bf(tile[tx][ty + 8 * r]);
    }
}

// ---------------- CSR build ----------------
__global__ void k_count(const int* __restrict__ dst, int* __restrict__ deg) {
    int e = blockIdx.x * 256 + threadIdx.x;
    if (e < NEDGES) atomicAdd(&deg[dst[e]], 1);
}

__global__ __launch_bounds__(1024) void k_scan(const int* __restrict__ deg, int* __restrict__ offs,
                                               int* __restrict__ cursor) {
    __shared__ int sums[1024];
    int t = threadIdx.x;
    int base = t * 32;
    int local[32];
    int s = 0;
#pragma unroll
    for (int i = 0; i < 32; i++) { local[i] = s; s += deg[base + i]; }
    sums[t] = s;
    __syncthreads();
    for (int d = 1; d < 1024; d <<= 1) {
        int v = (t >= d) ? sums[t - d] : 0;
        __syncthreads();
        sums[t] += v;
        __syncthreads();
    }
    int excl = (t == 0) ? 0 : sums[t - 1];
#pragma unroll
    for (int i = 0; i < 32; i++) {
        int o = excl + local[i];
        offs[base + i] = o;
        cursor[base + i] = o;
    }
    if (t == 1023) offs[NNODES] = sums[1023];
}

__global__ void k_scatter(const int* __restrict__ src, const int* __restrict__ dst,
                          int* __restrict__ cursor, int* __restrict__ ssrc) {
    int e = blockIdx.x * 256 + threadIdx.x;
    if (e < NEDGES) {
        int pos = atomicAdd(&cursor[dst[e]], 1);
        ssrc[pos] = src[e];
    }
}

// ---------------- fused layer-0 conv: lane-group-parallel 6-dim attention -> X bf16 ----------------
// lane = g*8+h: lane handles head h of node (block,wave)-base + g. 8 nodes per wave run their
// edge loops IN PARALLEL (R11 profile: serial-latency-bound, VALUBusy 40%, hbm 6%).
__global__ __launch_bounds__(256) void k_attn0(const float* __restrict__ x0, const float* __restrict__ C0,
                                               const float* __restrict__ Wv0, const float* __restrict__ bv0,
                                               const float* __restrict__ Ws0, const float* __restrict__ bs0,
                                               const int* __restrict__ offs, const int* __restrict__ ssrc,
                                               u16* __restrict__ Xout) {
    const int lane = threadIdx.x & 63;
    const int wv = threadIdx.x >> 6;
    const int g = lane >> 3;  // node slot
    const int h = lane & 7;   // head
    // per-lane column weights for epilogue (cols c = lane + 64*j)
    float wV[8][6], wS[8][6], bV[8], bS[8];
#pragma unroll
    for (int j = 0; j < 8; ++j) {
        int c = lane + 64 * j;
        bV[j] = bv0[c];
        bS[j] = bs0[c];
#pragma unroll
        for (int a = 0; a < 6; ++a) {
            wV[j][a] = Wv0[a * DDIM + c];
            wS[j][a] = Ws0[a * DDIM + c];
        }
    }
    // head constants
    float Ah[36], uh[6], wh[6], ch;
#pragma unroll
    for (int r = 0; r < 36; ++r) Ah[r] = C0[h * 49 + r];
#pragma unroll
    for (int a = 0; a < 6; ++a) uh[a] = C0[h * 49 + 36 + a];
#pragma unroll
    for (int a = 0; a < 6; ++a) wh[a] = C0[h * 49 + 42 + a];
    ch = C0[h * 49 + 48];

    const int node0 = (blockIdx.x * 4 + wv) * 8;
    const int node = node0 + g;
    float xi[6];
#pragma unroll
    for (int a = 0; a < 6; ++a) xi[a] = x0[(size_t)node * 6 + a];
    const int e0 = offs[node];
    const int deg = offs[node + 1] - e0;
    // wave-max deg (uniform within each 8-lane group)
    int dmax = deg;
    dmax = max(dmax, __shfl_xor(dmax, 8, 64));
    dmax = max(dmax, __shfl_xor(dmax, 16, 64));
    dmax = max(dmax, __shfl_xor(dmax, 32, 64));

    float m = -1e30f, l = 0.f;
    float xh[6];
#pragma unroll
    for (int a = 0; a < 6; ++a) xh[a] = 0.f;
    // prefetch edge 0
    float xj[6];
    {
        int s = (deg > 0) ? ssrc[e0] : 0;
#pragma unroll
        for (int a = 0; a < 6; ++a) xj[a] = x0[(size_t)s * 6 + a];
    }
    for (int e = 0; e < dmax; ++e) {
        float xc[6];
#pragma unroll
        for (int a = 0; a < 6; ++a) xc[a] = xj[a];
        const bool act = (e < deg);
        // prefetch next edge
        int sn = (e + 1 < deg) ? ssrc[e0 + e + 1] : 0;
#pragma unroll
        for (int a = 0; a < 6; ++a) xj[a] = x0[(size_t)sn * 6 + a];
        float alpha = ch;
#pragma unroll
        for (int a = 0; a < 6; ++a) {
            float t = uh[a];
#pragma unroll
            for (int b = 0; b < 6; ++b) t += Ah[a * 6 + b] * xc[b];
            alpha += xi[a] * t;
        }
#pragma unroll
        for (int b = 0; b < 6; ++b) alpha += wh[b] * xc[b];
        alpha *= 0.125f;
        float nm = act ? fmaxf(m, alpha) : m;
        float corr = __expf(m - nm);
        float p = act ? __expf(alpha - nm) : 0.f;
        l = l * corr + p;
#pragma unroll
        for (int a = 0; a < 6; ++a) xh[a] = xh[a] * corr + p * xc[a];
        m = nm;
    }
    // epilogue: node nn's head-j state lives in lane nn*8+j
#pragma unroll
    for (int nn = 0; nn < 8; ++nn) {
        int dnode = node0 + nn;
        float xin[6];
#pragma unroll
        for (int a = 0; a < 6; ++a) xin[a] = __shfl(xi[a], nn * 8, 64);
#pragma unroll
        for (int j = 0; j < 8; ++j) {
            int srcl = nn * 8 + j;
            float lb = __shfl(l, srcl, 64);
            float num = lb * bV[j];
#pragma unroll
            for (int a = 0; a < 6; ++a) num += __shfl(xh[a], srcl, 64) * wV[j][a];
            float skip = bS[j];
#pragma unroll
            for (int a = 0; a < 6; ++a) skip += xin[a] * wS[j][a];
            float r = num / (lb + 1e-16f) + skip;
            Xout[(size_t)dnode * DDIM + lane + 64 * j] = f2bf(fmaxf(r, 0.f));
        }
    }
}

// ---------------- main MFMA GEMM (bf16): X[32768,512] @ Wt[2048,512]^T -> Q8/KV8/S16 ----------------
// (256,4): R9 proved (256,5) clamps VGPR to 48 -> spill -> 5x traffic. Keep 4.
__global__ __launch_bounds__(256, 4) void k_gemm(const u16* __restrict__ X, const u16* __restrict__ Wt,
                                                 const float* __restrict__ bcat, u8* __restrict__ Q8,
                                                 u8* __restrict__ KV8, u16* __restrict__ S16) {
    __shared__ __align__(16) u16 smem[2 * 128 * 64];  // 32 KB
    u16* As = smem;
    u16* Bs = smem + 128 * 64;
    const int tid = threadIdx.x;
    const int lane = tid & 63;
    const int w = tid >> 6;
    const int wm = w & 1, wn = w >> 1;
    const int bid = blockIdx.x;
    const int xcd = bid & 7;
    const int s = bid >> 3;
    const size_t arow0 = (size_t)(xcd * 32 + (s >> 4)) * 128;
    const size_t brow0 = (size_t)(s & 15) * 128;
    const int bt = (int)(brow0 >> 7);

    f32x4 acc[4][4];
#pragma unroll
    for (int i = 0; i < 4; i++)
#pragma unroll
        for (int j = 0; j < 4; j++) acc[i][j] = (f32x4){0.f, 0.f, 0.f, 0.f};

    const int la = lane & 7;
    const int quad = lane >> 4;
    const int lm = lane & 15;

    for (int kt = 0; kt < 8; ++kt) {
        const int k0 = kt * 64;
#pragma unroll
        for (int t = 0; t < 4; ++t) {
            int idx = (w * 4 + t) * 64 + lane;
            int m = idx >> 3;
            int c = la ^ (m & 7);
            const u16* ga = X + (arow0 + m) * DDIM + (k0 + c * 8);
            const u16* gb = Wt + (brow0 + m) * DDIM + (k0 + c * 8);
            load_lds16(ga, &As[(size_t)((w * 4 + t) * 64) * 8]);
            load_lds16(gb, &Bs[(size_t)((w * 4 + t) * 64) * 8]);
        }
        __syncthreads();
#pragma unroll
        for (int kk = 0; kk < 2; ++kk) {
            bf16x8 af[4], bfg[4];
            int c = kk * 4 + quad;
#pragma unroll
            for (int i = 0; i < 4; ++i) {
                int m = wm * 64 + i * 16 + lm;
                int slot = m * 8 + (c ^ (m & 7));
                af[i] = *(const bf16x8*)&As[(size_t)slot * 8];
            }
#pragma unroll
            for (int j = 0; j < 4; ++j) {
                int n = wn * 64 + j * 16 + lm;
                int slot = n * 8 + (c ^ (n & 7));
                bfg[j] = *(const bf16x8*)&Bs[(size_t)slot * 8];
            }
#pragma unroll
            for (int i = 0; i < 4; ++i)
#pragma unroll
                for (int j = 0; j < 4; ++j)
                    acc[i][j] = __builtin_amdgcn_mfma_f32_16x16x32_bf16(af[i], bfg[j], acc[i][j], 0, 0, 0);
        }
        __syncthreads();
    }

    float biasv[4];
#pragma unroll
    for (int j = 0; j < 4; ++j) biasv[j] = bcat[brow0 + wn * 64 + j * 16 + lm];

    u16* stg = smem;  // [4 waves][32 rows][72 u16]
    const int chunk = lane & 7;
    const int rrow = lane >> 3;
    const int colbase = (int)brow0 + wn * 64 + chunk * 8;
#pragma unroll
    for (int p = 0; p < 2; ++p) {
        __syncthreads();
#pragma unroll
        for (int ii = 0; ii < 2; ++ii) {
            int i = p * 2 + ii;
#pragma unroll
            for (int j = 0; j < 4; ++j) {
#pragma unroll
                for (int r = 0; r < 4; ++r) {
                    int lr = ii * 16 + quad * 4 + r;
                    int lc = j * 16 + lm;
                    stg[(size_t)(w * 32 + lr) * 72 + lc] = f2bf(acc[i][j][r] + biasv[j]);
                }
            }
        }
        __syncthreads();
#pragma unroll
        for (int it = 0; it < 4; ++it) {
            int row = it * 8 + rrow;
            u16x8 v = *(const u16x8*)&stg[(size_t)(w * 32 + row) * 72 + chunk * 8];
            size_t grow = arow0 + wm * 64 + p * 32 + row;
            if (bt < 4) {
                float f[8];
#pragma unroll
                for (int j = 0; j < 8; j++) f[j] = bf2f(v[j]);
                int lo, hi;
                enc8(f, &lo, &hi);
                *(int2*)(Q8 + grow * 512 + colbase) = make_int2(lo, hi);
            } else if (bt < 12) {
                float f[8];
#pragma unroll
                for (int j = 0; j < 8; j++) f[j] = bf2f(v[j]);
                int lo, hi;
                enc8(f, &lo, &hi);
                *(int2*)(KV8 + grow * 1024 + (colbase - 512)) = make_int2(lo, hi);
            } else {
                *(u16x8*)(S16 + grow * 512 + (colbase - 1536)) = v;
            }
        }
    }
}

// ---------------- attention (layers 1-3): one wave per dst node, 4-deep KV batch (R8/R11-validated) ----------------
__global__ __launch_bounds__(256) void k_attn(const u8* __restrict__ Q8, const u8* __restrict__ KV8,
                                              const u16* __restrict__ S16, const int* __restrict__ offs,
                                              const int* __restrict__ ssrc, u16* __restrict__ Xout) {
    const int lane = threadIdx.x & 63;
    const int node = blockIdx.x * 4 + (threadIdx.x >> 6);
    const u64 q8 = *(const u64*)(Q8 + (size_t)node * 512 + (size_t)lane * 8);
    const u16x8 sv = *(const u16x8*)(S16 + (size_t)node * 512 + (size_t)lane * 8);  // hoisted: independent
    float qf[8];
    dec8((int)(q8 & 0xFFFFFFFFull), (int)(q8 >> 32), qf);
    float m = -INFINITY, l = 0.f;
    float acc[8];
#pragma unroll
    for (int j = 0; j < 8; j++) acc[j] = 0.f;
    const int e0 = offs[node], e1 = offs[node + 1];
    int e = e0;
    while (e < e1) {
        int nb = e1 - e;
        if (nb > 4) nb = 4;
        int4 kvb[4];
#pragma unroll
        for (int i = 0; i < 4; ++i) {
            if (i < nb) {
                int s = ssrc[e + i];
                kvb[i] = *(const int4*)(KV8 + (size_t)s * 1024 + (size_t)lane * 16);
            }
        }
#pragma unroll
        for (int i = 0; i < 4; ++i) {
            if (i >= nb) break;
            int4 kv = kvb[i];
            f32x2 k01 = __builtin_amdgcn_cvt_pk_f32_fp8(kv.x, false);
            f32x2 k23 = __builtin_amdgcn_cvt_pk_f32_fp8(kv.x, true);
            f32x2 k45 = __builtin_amdgcn_cvt_pk_f32_fp8(kv.y, false);
            f32x2 k67 = __builtin_amdgcn_cvt_pk_f32_fp8(kv.y, true);
            float d = qf[0] * k01[0] + qf[1] * k01[1] + qf[2] * k23[0] + qf[3] * k23[1] +
                      qf[4] * k45[0] + qf[5] * k45[1] + qf[6] * k67[0] + qf[7] * k67[1];
            d += __shfl_xor(d, 1, 64);
            d += __shfl_xor(d, 2, 64);
            d += __shfl_xor(d, 4, 64);
            float a = d * 0.125f;
            float nm = fmaxf(m, a);
            float corr = __expf(m - nm);
            float p = __expf(a - nm);
            l = l * corr + p;
            f32x2 v01 = __builtin_amdgcn_cvt_pk_f32_fp8(kv.z, false);
            f32x2 v23 = __builtin_amdgcn_cvt_pk_f32_fp8(kv.z, true);
            f32x2 v45 = __builtin_amdgcn_cvt_pk_f32_fp8(kv.w, false);
            f32x2 v67 = __builtin_amdgcn_cvt_pk_f32_fp8(kv.w, true);
            acc[0] = acc[0] * corr + p * v01[0];
            acc[1] = acc[1] * corr + p * v01[1];
            acc[2] = acc[2] * corr + p * v23[0];
            acc[3] = acc[3] * corr + p * v23[1];
            acc[4] = acc[4] * corr + p * v45[0];
            acc[5] = acc[5] * corr + p * v45[1];
            acc[6] = acc[6] * corr + p * v67[0];
            acc[7] = acc[7] * corr + p * v67[1];
            m = nm;
        }
        e += nb;
    }
    float inv = 1.0f / (l + 1e-16f);
    u16x8 o;
#pragma unroll
    for (int j = 0; j < 8; j++) {
        float r = acc[j] * inv + bf2f(sv[j]);
        o[j] = f2bf(fmaxf(r, 0.f));
    }
    *(u16x8*)(Xout + (size_t)node * DDIM + (size_t)lane * 8) = o;
}

// ---------------- pooling (bf16 input, vectorized) ----------------
__global__ __launch_bounds__(256) void k_pool(const u16* __restrict__ X, float* __restrict__ pooled) {
    __shared__ float red[4][64][8];
    int t = threadIdx.x;
    int chunk = t & 63;
    int rofs = t >> 6;
    float s[8];
#pragma unroll
    for (int j = 0; j < 8; j++) s[j] = 0.f;
    int nd0 = blockIdx.x * 256;
    for (int nd = nd0 + rofs; nd < nd0 + 256; nd += 4) {
        u16x8 v = *(const u16x8*)&X[(size_t)nd * DDIM + chunk * 8];
#pragma unroll
        for (int j = 0; j < 8; j++) s[j] += bf2f(v[j]);
    }
#pragma unroll
    for (int j = 0; j < 8; j++) red[rofs][chunk][j] = s[j];
    __syncthreads();
    if (t < 64) {
#pragma unroll
        for (int j = 0; j < 8; j++) {
            float o = red[0][t][j] + red[1][t][j] + red[2][t][j] + red[3][t][j];
            atomicAdd(&pooled[t * 8 + j], o);
        }
    }
}

// ---------------- heads: emb + hidden layers + critic ----------------
__global__ __launch_bounds__(1024) void k_heads(const float* __restrict__ pooled, const float* __restrict__ fcW,
                                                const float* __restrict__ fcb, const float* __restrict__ ui,
                                                const float* __restrict__ sp, const float* __restrict__ aW1,
                                                const float* __restrict__ ab1, const float* __restrict__ cW1,
                                                const float* __restrict__ cb1, const float* __restrict__ cW2,
                                                const float* __restrict__ cb2, float* __restrict__ hidden_a,
                                                float* __restrict__ out) {
    __shared__ float spool[512];
    __shared__ float semb[64];
    __shared__ float shc[8][128];
    int t = threadIdx.x;
    if (t < 512) spool[t] = pooled[t] * (1.0f / 32768.0f);
    __syncthreads();
    if (t < 64) {
        float s = fcb[t];
        for (int k = 0; k < 512; k++) s += spool[k] * fcW[k * 64 + t];
        semb[t] = s;
    }
    __syncthreads();
    int u = t >> 7, j = t & 127;
    float u0 = ui[u * 2], u1 = ui[u * 2 + 1], uspd = sp[u];
    float ha = ab1[j] + u0 * aW1[j] + u1 * aW1[128 + j] + uspd * aW1[66 * 128 + j];
    float hc = cb1[j] + u0 * cW1[j] + u1 * cW1[128 + j] + uspd * cW1[66 * 128 + j];
    for (int k = 0; k < 64; k++) {
        float e = semb[k];
        ha += e * aW1[(2 + k) * 128 + j];
        hc += e * cW1[(2 + k) * 128 + j];
    }
    ha = fmaxf(ha, 0.f);
    hc = fmaxf(hc, 0.f);
    hidden_a[u * 128 + j] = ha;
    shc[u][j] = hc;
    __syncthreads();
    if (t < 8) {
        float s = cb2[0];
        for (int k = 0; k < 128; k++) s += shc[t][k] * cW2[k];
        out[NNODES + t] = s;
    }
}

// ---------------- actor logits + softmax ----------------
__global__ __launch_bounds__(1024) void k_actor(const float* __restrict__ hidden_a, const float* __restrict__ aW2,
                                                const float* __restrict__ ab2, float* __restrict__ out) {
    __shared__ float h[128];
    __shared__ float red[1024];
    int u = blockIdx.x, t = threadIdx.x;
    if (t < 128) h[t] = hidden_a[u * 128 + t];
    __syncthreads();
    float lg[4];
#pragma unroll
    for (int p = 0; p < 4; p++) {
        int mcol = t + p * 1024;
        float s = ab2[mcol];
        for (int k = 0; k < 128; k++) s += h[k] * aW2[(size_t)k * MM + mcol];
        lg[p] = s;
    }
    float mx = fmaxf(fmaxf(lg[0], lg[1]), fmaxf(lg[2], lg[3]));
    red[t] = mx;
    __syncthreads();
    for (int s2 = 512; s2 > 0; s2 >>= 1) {
        if (t < s2) red[t] = fmaxf(red[t], red[t + s2]);
        __syncthreads();
    }
    mx = red[0];
    __syncthreads();
    float e[4], sum = 0.f;
#pragma unroll
    for (int p = 0; p < 4; p++) {
        e[p] = __expf(lg[p] - mx);
        sum += e[p];
    }
    red[t] = sum;
    __syncthreads();
    for (int s2 = 512; s2 > 0; s2 >>= 1) {
        if (t < s2) red[t] += red[t + s2];
        __syncthreads();
    }
    float inv = 1.0f / red[0];
#pragma unroll
    for (int p = 0; p < 4; p++) out[(size_t)u * MM + t + p * 1024] = e[p] * inv;
}

extern "C" void kernel_launch(void* const* d_in, const int* in_sizes, int n_in,
                              void* d_out, int out_size, void* d_ws, size_t ws_size,
                              hipStream_t stream) {
    const float* mc   = (const float*)d_in[0];
    const float* ui   = (const float*)d_in[1];
    const float* sp   = (const float*)d_in[2];
    const float* cm   = (const float*)d_in[3];
    const float* at   = (const float*)d_in[4];
    const int*   eidx = (const int*)d_in[5];
    const int*   mask = (const int*)d_in[7];
    const float* Wq0 = (const float*)d_in[8];
    const float* bq0 = (const float*)d_in[9];
    const float* Wk0 = (const float*)d_in[10];
    const float* bk0 = (const float*)d_in[11];
    const float* Wv0 = (const float*)d_in[12];
    const float* bv0 = (const float*)d_in[13];
    const float* Ws0 = (const float*)d_in[14];
    const float* bs0 = (const float*)d_in[15];
    const float* Wq = (const float*)d_in[16];
    const float* bq = (const float*)d_in[17];
    const float* Wk = (const float*)d_in[18];
    const float* bk = (const float*)d_in[19];
    const float* Wv = (const float*)d_in[20];
    const float* bv = (const float*)d_in[21];
    const float* Ws = (const float*)d_in[22];
    const float* bs = (const float*)d_in[23];
    const float* fcW = (const float*)d_in[24];
    const float* fcb = (const float*)d_in[25];
    const float* aW1 = (const float*)d_in[26];
    const float* ab1 = (const float*)d_in[27];
    const float* aW2 = (const float*)d_in[28];
    const float* ab2 = (const float*)d_in[29];
    const float* cW1 = (const float*)d_in[30];
    const float* cb1 = (const float*)d_in[31];
    const float* cW2 = (const float*)d_in[32];
    const float* cb2 = (const float*)d_in[33];
    float* out = (float*)d_out;

    const int* esrc = eidx;
    const int* edst = eidx + NEDGES;

    char* ws = (char*)d_ws;
    size_t off = 0;
    auto alloc = [&](size_t bytes) -> void* {
        void* p = ws + off;
        off += (bytes + 255) & ~(size_t)255;
        return p;
    };
    u8*    Q8    = (u8*)alloc((size_t)NNODES * 512);         // 16 MB fp8
    u8*    KV8   = (u8*)alloc((size_t)NNODES * 1024);        // 32 MB fp8 interleaved
    u16*   S16   = (u16*)alloc((size_t)NNODES * 512 * 2);    // 32 MB bf16
    u16*   X     = (u16*)alloc((size_t)NNODES * DDIM * 2);   // 32 MB bf16
    u16*   Wt    = (u16*)alloc((size_t)3 * QK4 * DDIM * 2);  // 6 MB
    float* bcat  = (float*)alloc((size_t)3 * QK4 * 4);
    float* C0    = (float*)alloc((size_t)392 * 4);
    float* x0    = (float*)alloc((size_t)NNODES * 6 * 4);
    int*   deg   = (int*)alloc((size_t)NNODES * 4);
    int*   offs  = (int*)alloc((size_t)(NNODES + 1) * 4);
    int*   cursor= (int*)alloc((size_t)NNODES * 4);
    int*   ssrc  = (int*)alloc((size_t)NEDGES * 4);
    float* pooled= (float*)alloc((size_t)512 * 4);
    float* hidden_a = (float*)alloc((size_t)UU * 128 * 4);
    (void)ws_size; (void)in_sizes; (void)n_in; (void)out_size;

    // prep
    k_prep<<<154, 256, 0, stream>>>(mc, mask, sp, cm, at, x0, bq, bk, bv, bs, bcat, deg, pooled);
    k_c0<<<1, 512, 0, stream>>>(Wq0, bq0, Wk0, bk0, C0);
    {
        dim3 g(16, 16, 12), b(32, 8);
        k_wt<<<g, b, 0, stream>>>(Wq, Wk, Wv, Ws, Wt);
    }
    // CSR
    k_count<<<NEDGES / 256, 256, 0, stream>>>(edst, deg);
    k_scan<<<1, 1024, 0, stream>>>(deg, offs, cursor);
    k_scatter<<<NEDGES / 256, 256, 0, stream>>>(esrc, edst, cursor, ssrc);

    // layer 0: fused 6-dim attention + projection (lane-group-parallel)
    k_attn0<<<1024, 256, 0, stream>>>(x0, C0, Wv0, bv0, Ws0, bs0, offs, ssrc, X);

    // layers 1..3
    for (int l = 0; l < 3; ++l) {
        k_gemm<<<4096, 256, 0, stream>>>(X, Wt + (size_t)l * QK4 * DDIM, bcat + (size_t)l * QK4, Q8, KV8, S16);
        k_attn<<<NNODES / 4, 256, 0, stream>>>(Q8, KV8, S16, offs, ssrc, X);
    }

    // pool + heads
    k_pool<<<128, 256, 0, stream>>>(X, pooled);
    k_heads<<<1, 1024, 0, stream>>>(pooled, fcW, fcb, ui, sp, aW1, ab1, cW1, cb1, cW2, cb2, hidden_a, out);
    k_actor<<<UU, 1024, 0, stream>>>(hidden_a, aW2, ab2, out);
}